// Round 3
// baseline (1490.347 us; speedup 1.0000x reference)
//
#include <hip/hip_runtime.h>
#include <cstdint>

#define NCH 128
#define NGRAPHS 64
#define OUTC 10
#define POOL_CHUNK 256

// ---------------- preprocessing ----------------

__global__ __launch_bounds__(256) void hist_kernel(const int* __restrict__ ei,
                                                   int* __restrict__ sc,
                                                   int* __restrict__ dc, int E) {
  int i = blockIdx.x * 256 + threadIdx.x;
  if (i >= E) return;
  atomicAdd(&sc[ei[i]], 1);       // src degree (reference's `deg` over row)
  atomicAdd(&dc[ei[E + i]], 1);   // dst counts for CSR
}

__global__ __launch_bounds__(256) void dis_kernel(const int* __restrict__ sc,
                                                  float* __restrict__ dis, int N) {
  int i = blockIdx.x * 256 + threadIdx.x;
  if (i < N) {
    int d = sc[i];
    dis[i] = d > 0 ? rsqrtf((float)d) : 0.0f;
  }
}

__global__ __launch_bounds__(256) void scanA_kernel(const int* __restrict__ cnt,
                                                    int* __restrict__ bsum, int N) {
  __shared__ int wred[4];
  int t = threadIdx.x;
  int idx = blockIdx.x * 1024 + t * 4;
  int s = 0;
#pragma unroll
  for (int j = 0; j < 4; ++j)
    if (idx + j < N) s += cnt[idx + j];
  for (int d = 32; d; d >>= 1) s += __shfl_down(s, d);
  if ((t & 63) == 0) wred[t >> 6] = s;
  __syncthreads();
  if (t == 0) bsum[blockIdx.x] = wred[0] + wred[1] + wred[2] + wred[3];
}

__global__ void scanB_kernel(int* __restrict__ bsum, int nb) {
  __shared__ int wtot[2];
  __shared__ int carry_s;
  int t = threadIdx.x;  // 128 threads
  if (t == 0) carry_s = 0;
  __syncthreads();
  for (int base = 0; base < nb; base += 128) {
    int i = base + t;
    int v = (i < nb) ? bsum[i] : 0;
    int lane = t & 63, w = t >> 6;
    int ps = v;
    for (int d = 1; d < 64; d <<= 1) {
      int o = __shfl_up(ps, d);
      if (lane >= d) ps += o;
    }
    if (lane == 63) wtot[w] = ps;
    __syncthreads();
    int excl = ps - v + (w ? wtot[0] : 0) + carry_s;
    if (i < nb) bsum[i] = excl;
    __syncthreads();
    if (t == 0) carry_s += wtot[0] + wtot[1];
    __syncthreads();
  }
}

__global__ __launch_bounds__(256) void scanC_kernel(const int* __restrict__ cnt,
                                                    const int* __restrict__ bsum,
                                                    int* __restrict__ rp,
                                                    int* __restrict__ nxt, int N, int E) {
  __shared__ int wsum[4];
  int t = threadIdx.x;
  int idx = blockIdx.x * 1024 + t * 4;
  int v[4];
#pragma unroll
  for (int j = 0; j < 4; ++j) v[j] = (idx + j < N) ? cnt[idx + j] : 0;
  int s = v[0] + v[1] + v[2] + v[3];
  int lane = t & 63, w = t >> 6;
  int ps = s;
  for (int d = 1; d < 64; d <<= 1) {
    int o = __shfl_up(ps, d);
    if (lane >= d) ps += o;
  }
  if (lane == 63) wsum[w] = ps;
  __syncthreads();
  int woff = 0;
  for (int i = 0; i < w; ++i) woff += wsum[i];
  int off = bsum[blockIdx.x] + woff + ps - s;
#pragma unroll
  for (int j = 0; j < 4; ++j) {
    if (idx + j < N) {
      rp[idx + j] = off;
      nxt[idx + j] = off;
      off += v[j];
    }
  }
  if (blockIdx.x == 0 && t == 0) rp[N] = E;
}

__global__ __launch_bounds__(256) void scatter_kernel(const int* __restrict__ ei,
                                                      const float* __restrict__ dis,
                                                      int* __restrict__ nxt,
                                                      int* __restrict__ ssrc,
                                                      float* __restrict__ snorm, int E) {
  int i = blockIdx.x * 256 + threadIdx.x;
  if (i >= E) return;
  int s = ei[i];
  int d = ei[E + i];
  int pos = atomicAdd(&nxt[d], 1);
  ssrc[pos] = s;
  snorm[pos] = -dis[s] * dis[d];
}

// ---------------- propagate: out[i] = sum_e norm_e * h[src_e] ----------------

__global__ __launch_bounds__(256) void prop_kernel(const float* __restrict__ h,
                                                   float* __restrict__ out,
                                                   const int* __restrict__ rp,
                                                   const int* __restrict__ ssrc,
                                                   const float* __restrict__ snorm, int N) {
  int node = blockIdx.x * 4 + (threadIdx.x >> 6);
  if (node >= N) return;
  int lane = threadIdx.x & 63;
  int c = lane * 2;
  int e = rp[node], e1 = rp[node + 1];
  float ax = 0.f, ay = 0.f;
  // 4-deep unroll: 4 independent gathers in flight per wave (latency hiding)
  for (; e + 3 < e1; e += 4) {
    int s0 = ssrc[e], s1 = ssrc[e + 1], s2 = ssrc[e + 2], s3 = ssrc[e + 3];
    float w0 = snorm[e], w1 = snorm[e + 1], w2 = snorm[e + 2], w3 = snorm[e + 3];
    float2 h0 = *(const float2*)&h[s0 * NCH + c];
    float2 h1 = *(const float2*)&h[s1 * NCH + c];
    float2 h2 = *(const float2*)&h[s2 * NCH + c];
    float2 h3 = *(const float2*)&h[s3 * NCH + c];
    ax += w0 * h0.x; ay += w0 * h0.y;
    ax += w1 * h1.x; ay += w1 * h1.y;
    ax += w2 * h2.x; ay += w2 * h2.y;
    ax += w3 * h3.x; ay += w3 * h3.y;
  }
  for (; e < e1; ++e) {
    int s0 = ssrc[e];
    float w0 = snorm[e];
    float2 h0 = *(const float2*)&h[s0 * NCH + c];
    ax += w0 * h0.x; ay += w0 * h0.y;
  }
  float2 r; r.x = ax; r.y = ay;
  *(float2*)&out[node * NCH + c] = r;
}

// ---------------- fused Cheb GEMM: out = h@W0 + p1@W1 + (2*p2 - h)@W2 + b ----------------
// NOTE: out may alias h (and/or p1/p2): each block stages its own rows of
// h/p1/p2 into LDS before the last __syncthreads(), and only writes those
// same rows in the epilogue after that barrier; blocks own disjoint rows.
// Therefore NO __restrict__ on h/p1/p2/out.

__global__ __launch_bounds__(256) void gemm_cheb_kernel(
    const float* h, const float* p1, const float* p2,
    const float* __restrict__ W, const float* __restrict__ bias,
    float* out, int N, int relu) {
  __shared__ float As[32][132];  // [k][row], pad 132 -> 2-way read conflicts (free)
  __shared__ float Bs[32][128];  // [k][col]
  int t = threadIdx.x;
  int tr = t & 15, tc = t >> 4;
  int rowBase = blockIdx.x * 128;
  float acc[2][2][4][4];
#pragma unroll
  for (int a = 0; a < 2; ++a)
#pragma unroll
    for (int b = 0; b < 2; ++b)
#pragma unroll
      for (int i = 0; i < 4; ++i)
#pragma unroll
        for (int j = 0; j < 4; ++j) acc[a][b][i][j] = 0.f;

  int lrow = t >> 3;      // 0..31
  int lk = (t & 7) * 4;   // 0,4,...,28
  int bk = t >> 5;        // 0..7
  int bj = (t & 31) * 4;  // 0..124

  for (int phase = 0; phase < 3; ++phase) {
    const float* __restrict__ Wp = W + phase * (NCH * NCH);
    for (int ks = 0; ks < 4; ++ks) {
      int c0 = ks * 32;
      __syncthreads();
#pragma unroll
      for (int pass = 0; pass < 4; ++pass) {
        int row = pass * 32 + lrow;
        int gRow = rowBase + row;
        float4 av = make_float4(0.f, 0.f, 0.f, 0.f);
        if (gRow < N) {
          int base = gRow * NCH + c0 + lk;
          if (phase == 0) {
            av = *(const float4*)&h[base];
          } else if (phase == 1) {
            av = *(const float4*)&p1[base];
          } else {
            float4 a2 = *(const float4*)&p2[base];
            float4 a0 = *(const float4*)&h[base];
            av.x = 2.f * a2.x - a0.x; av.y = 2.f * a2.y - a0.y;
            av.z = 2.f * a2.z - a0.z; av.w = 2.f * a2.w - a0.w;
          }
        }
        As[lk + 0][row] = av.x;
        As[lk + 1][row] = av.y;
        As[lk + 2][row] = av.z;
        As[lk + 3][row] = av.w;
      }
#pragma unroll
      for (int pass = 0; pass < 4; ++pass) {
        int kloc = pass * 8 + bk;
        *(float4*)&Bs[kloc][bj] = *(const float4*)&Wp[(c0 + kloc) * NCH + bj];
      }
      __syncthreads();
#pragma unroll
      for (int k = 0; k < 32; ++k) {
        float4 a0 = *(const float4*)&As[k][tr * 4];
        float4 a1 = *(const float4*)&As[k][64 + tr * 4];
        float4 b0 = *(const float4*)&Bs[k][tc * 4];
        float4 b1 = *(const float4*)&Bs[k][64 + tc * 4];
        float ar[2][4] = {{a0.x, a0.y, a0.z, a0.w}, {a1.x, a1.y, a1.z, a1.w}};
        float br[2][4] = {{b0.x, b0.y, b0.z, b0.w}, {b1.x, b1.y, b1.z, b1.w}};
#pragma unroll
        for (int a = 0; a < 2; ++a)
#pragma unroll
          for (int b = 0; b < 2; ++b)
#pragma unroll
            for (int i = 0; i < 4; ++i)
#pragma unroll
              for (int j = 0; j < 4; ++j) acc[a][b][i][j] += ar[a][i] * br[b][j];
      }
    }
  }
#pragma unroll
  for (int a = 0; a < 2; ++a) {
#pragma unroll
    for (int i = 0; i < 4; ++i) {
      int gRow = rowBase + a * 64 + tr * 4 + i;
      if (gRow >= N) continue;
#pragma unroll
      for (int b = 0; b < 2; ++b) {
        int col = b * 64 + tc * 4;
        float4 v;
        v.x = acc[a][b][i][0] + bias[col + 0];
        v.y = acc[a][b][i][1] + bias[col + 1];
        v.z = acc[a][b][i][2] + bias[col + 2];
        v.w = acc[a][b][i][3] + bias[col + 3];
        if (relu) {
          v.x = fmaxf(v.x, 0.f); v.y = fmaxf(v.y, 0.f);
          v.z = fmaxf(v.z, 0.f); v.w = fmaxf(v.w, 0.f);
        }
        *(float4*)&out[gRow * NCH + col] = v;
      }
    }
  }
}

// ---------------- pooling + final linear ----------------

__global__ __launch_bounds__(128) void pool_kernel(const float* __restrict__ h,
                                                   const int* __restrict__ batch,
                                                   float* __restrict__ sums,
                                                   float* __restrict__ gcnt, int N) {
  int start = blockIdx.x * POOL_CHUNK;
  if (start >= N) return;
  int end = min(start + POOL_CHUNK, N);
  int c = threadIdx.x;
  float acc = 0.f;
  int cnt = 0;
  int cur = batch[start];
  for (int i = start; i < end; ++i) {
    int g = batch[i];
    if (g != cur) {
      atomicAdd(&sums[cur * NCH + c], acc);
      if (c == 0) atomicAdd(&gcnt[cur], (float)cnt);
      acc = 0.f; cnt = 0; cur = g;
    }
    acc += h[i * NCH + c];
    ++cnt;
  }
  atomicAdd(&sums[cur * NCH + c], acc);
  if (c == 0) atomicAdd(&gcnt[cur], (float)cnt);
}

__global__ void final_kernel(const float* __restrict__ sums, const float* __restrict__ gcnt,
                             const float* __restrict__ lw, const float* __restrict__ lb,
                             float* __restrict__ out) {
  int g = blockIdx.x;
  int o = threadIdx.x;
  if (o >= OUTC) return;
  float inv = 1.0f / fmaxf(gcnt[g], 1.0f);
  float acc = lb[o];
  for (int ch = 0; ch < NCH; ++ch) acc += sums[g * NCH + ch] * inv * lw[ch * OUTC + o];
  out[g * OUTC + o] = acc;
}

// ---------------- launch ----------------

extern "C" void kernel_launch(void* const* d_in, const int* in_sizes, int n_in,
                              void* d_out, int out_size, void* d_ws, size_t ws_size,
                              hipStream_t stream) {
  const float* x  = (const float*)d_in[0];
  const int* ei   = (const int*)d_in[1];
  const int* batch= (const int*)d_in[2];
  const float* W0 = (const float*)d_in[3];
  const float* b0 = (const float*)d_in[4];
  const float* W1 = (const float*)d_in[5];
  const float* b1 = (const float*)d_in[6];
  const float* W2 = (const float*)d_in[7];
  const float* b2 = (const float*)d_in[8];
  const float* lw = (const float*)d_in[9];
  const float* lb = (const float*)d_in[10];
  float* out = (float*)d_out;
  int N = in_sizes[0] / NCH;
  int E = in_sizes[1] / 2;

  char* ws = (char*)d_ws;
  size_t off = 0;
  auto take = [&](size_t bytes) -> char* {
    char* p = ws + off;
    off += (bytes + 511) & ~(size_t)511;
    return p;
  };
  int* sc      = (int*)take((size_t)N * 4);
  int* dc      = (int*)take((size_t)N * 4);
  float* dis   = (float*)take((size_t)N * 4);
  int* rp      = (int*)take((size_t)(N + 1) * 4);
  int* nxt     = (int*)take((size_t)N * 4);
  int* bsum    = (int*)take(1024 * 4);
  int* ssrc    = (int*)take((size_t)E * 4);
  float* snorm = (float*)take((size_t)E * 4);
  // three rotating feature buffers (gemm output aliases its h input)
  float* A     = (float*)take((size_t)N * NCH * 4);
  float* B     = (float*)take((size_t)N * NCH * 4);
  float* D     = (float*)take((size_t)N * NCH * 4);
  float* sums  = (float*)take((size_t)NGRAPHS * NCH * 4);
  float* gcnt  = (float*)take((size_t)NGRAPHS * 4);

  int nb = (N + 1023) / 1024;

  hipMemsetAsync(sc, 0, (size_t)N * 4, stream);
  hipMemsetAsync(dc, 0, (size_t)N * 4, stream);
  hipMemsetAsync(sums, 0, (size_t)NGRAPHS * NCH * 4, stream);
  hipMemsetAsync(gcnt, 0, (size_t)NGRAPHS * 4, stream);

  hist_kernel<<<(E + 255) / 256, 256, 0, stream>>>(ei, sc, dc, E);
  dis_kernel<<<(N + 255) / 256, 256, 0, stream>>>(sc, dis, N);
  scanA_kernel<<<nb, 256, 0, stream>>>(dc, bsum, N);
  scanB_kernel<<<1, 128, 0, stream>>>(bsum, nb);
  scanC_kernel<<<nb, 256, 0, stream>>>(dc, bsum, rp, nxt, N, E);
  scatter_kernel<<<(E + 255) / 256, 256, 0, stream>>>(ei, dis, nxt, ssrc, snorm, E);

  int pgrid = (N + 3) / 4;
  int ggrid = (N + 127) / 128;

  // layer 0: Tx1=A, Tx2-prop=B, H1=D
  prop_kernel<<<pgrid, 256, 0, stream>>>(x, A, rp, ssrc, snorm, N);
  prop_kernel<<<pgrid, 256, 0, stream>>>(A, B, rp, ssrc, snorm, N);
  gemm_cheb_kernel<<<ggrid, 256, 0, stream>>>(x, A, B, W0, b0, D, N, 1);
  // layer 1: H1=D -> H2=D (out aliases h; safe per kernel comment)
  prop_kernel<<<pgrid, 256, 0, stream>>>(D, A, rp, ssrc, snorm, N);
  prop_kernel<<<pgrid, 256, 0, stream>>>(A, B, rp, ssrc, snorm, N);
  gemm_cheb_kernel<<<ggrid, 256, 0, stream>>>(D, A, B, W1, b1, D, N, 1);
  // layer 2: H2=D -> H3=D
  prop_kernel<<<pgrid, 256, 0, stream>>>(D, A, rp, ssrc, snorm, N);
  prop_kernel<<<pgrid, 256, 0, stream>>>(A, B, rp, ssrc, snorm, N);
  gemm_cheb_kernel<<<ggrid, 256, 0, stream>>>(D, A, B, W2, b2, D, N, 0);

  pool_kernel<<<(N + POOL_CHUNK - 1) / POOL_CHUNK, 128, 0, stream>>>(D, batch, sums, gcnt, N);
  final_kernel<<<NGRAPHS, 16, 0, stream>>>(sums, gcnt, lw, lb, out);
}

// Round 4
// 1362.545 us; speedup vs baseline: 1.0938x; 1.0938x over previous
//
#include <hip/hip_runtime.h>
#include <cstdint>

#define NCH 128
#define NGRAPHS 64
#define OUTC 10
#define POOL_CHUNK 256

typedef __attribute__((ext_vector_type(8))) short s8v;
typedef __attribute__((ext_vector_type(4))) float f4v;

// float -> bf16(hi) + bf16(lo), RNE. a ~= hi + lo to ~2^-18 rel.
__device__ __forceinline__ void bf16split(float a, unsigned short& hi, unsigned short& lo) {
  union { float f; unsigned u; } x; x.f = a;
  unsigned r = x.u + 0x7fffu + ((x.u >> 16) & 1u);
  hi = (unsigned short)(r >> 16);
  union { unsigned u; float f; } hf; hf.u = ((unsigned)hi) << 16;
  float res = a - hf.f;               // exact (Sterbenz)
  union { float f; unsigned u; } y; y.f = res;
  unsigned r2 = y.u + 0x7fffu + ((y.u >> 16) & 1u);
  lo = (unsigned short)(r2 >> 16);
}

// ---------------- preprocessing ----------------

__global__ __launch_bounds__(256) void hist_kernel(const int* __restrict__ ei,
                                                   int* __restrict__ sc,
                                                   int* __restrict__ dc, int E) {
  int i = blockIdx.x * 256 + threadIdx.x;
  if (i >= E) return;
  atomicAdd(&sc[ei[i]], 1);
  atomicAdd(&dc[ei[E + i]], 1);
}

__global__ __launch_bounds__(256) void dis_kernel(const int* __restrict__ sc,
                                                  float* __restrict__ dis, int N) {
  int i = blockIdx.x * 256 + threadIdx.x;
  if (i < N) {
    int d = sc[i];
    dis[i] = d > 0 ? rsqrtf((float)d) : 0.0f;
  }
}

__global__ __launch_bounds__(256) void scanA_kernel(const int* __restrict__ cnt,
                                                    int* __restrict__ bsum, int N) {
  __shared__ int wred[4];
  int t = threadIdx.x;
  int idx = blockIdx.x * 1024 + t * 4;
  int s = 0;
#pragma unroll
  for (int j = 0; j < 4; ++j)
    if (idx + j < N) s += cnt[idx + j];
  for (int d = 32; d; d >>= 1) s += __shfl_down(s, d);
  if ((t & 63) == 0) wred[t >> 6] = s;
  __syncthreads();
  if (t == 0) bsum[blockIdx.x] = wred[0] + wred[1] + wred[2] + wred[3];
}

__global__ void scanB_kernel(int* __restrict__ bsum, int nb) {
  __shared__ int wtot[2];
  __shared__ int carry_s;
  int t = threadIdx.x;  // 128 threads
  if (t == 0) carry_s = 0;
  __syncthreads();
  for (int base = 0; base < nb; base += 128) {
    int i = base + t;
    int v = (i < nb) ? bsum[i] : 0;
    int lane = t & 63, w = t >> 6;
    int ps = v;
    for (int d = 1; d < 64; d <<= 1) {
      int o = __shfl_up(ps, d);
      if (lane >= d) ps += o;
    }
    if (lane == 63) wtot[w] = ps;
    __syncthreads();
    int excl = ps - v + (w ? wtot[0] : 0) + carry_s;
    if (i < nb) bsum[i] = excl;
    __syncthreads();
    if (t == 0) carry_s += wtot[0] + wtot[1];
    __syncthreads();
  }
}

__global__ __launch_bounds__(256) void scanC_kernel(const int* __restrict__ cnt,
                                                    const int* __restrict__ bsum,
                                                    int* __restrict__ rp,
                                                    int* __restrict__ nxt, int N, int E) {
  __shared__ int wsum[4];
  int t = threadIdx.x;
  int idx = blockIdx.x * 1024 + t * 4;
  int v[4];
#pragma unroll
  for (int j = 0; j < 4; ++j) v[j] = (idx + j < N) ? cnt[idx + j] : 0;
  int s = v[0] + v[1] + v[2] + v[3];
  int lane = t & 63, w = t >> 6;
  int ps = s;
  for (int d = 1; d < 64; d <<= 1) {
    int o = __shfl_up(ps, d);
    if (lane >= d) ps += o;
  }
  if (lane == 63) wsum[w] = ps;
  __syncthreads();
  int woff = 0;
  for (int i = 0; i < w; ++i) woff += wsum[i];
  int off = bsum[blockIdx.x] + woff + ps - s;
#pragma unroll
  for (int j = 0; j < 4; ++j) {
    if (idx + j < N) {
      rp[idx + j] = off;
      nxt[idx + j] = off;
      off += v[j];
    }
  }
  if (blockIdx.x == 0 && t == 0) rp[N] = E;
}

__global__ __launch_bounds__(256) void scatter_kernel(const int* __restrict__ ei,
                                                      const float* __restrict__ dis,
                                                      int* __restrict__ nxt,
                                                      int* __restrict__ ssrc,
                                                      float* __restrict__ snorm, int E) {
  int i = blockIdx.x * 256 + threadIdx.x;
  if (i >= E) return;
  int s = ei[i];
  int d = ei[E + i];
  int pos = atomicAdd(&nxt[d], 1);
  ssrc[pos] = s;
  snorm[pos] = -dis[s] * dis[d];
}

// --- weight prep: transpose + bf16 hi/lo split into MFMA-fragment-linear layout ---
// Output layout per layer L, phase p: [kwin 0..3][ct 0..7][lane 0..63][j 0..7]
// element = W_L[p][k][col], k = kwin*32 + (lane>>4)*8 + j, col = ct*16 + (lane&15)
__global__ __launch_bounds__(256) void prep_w_kernel(const float* __restrict__ W0,
                                                     const float* __restrict__ W1,
                                                     const float* __restrict__ W2,
                                                     unsigned short* __restrict__ WFhi,
                                                     unsigned short* __restrict__ WFlo) {
  int idx = blockIdx.x * 256 + threadIdx.x;
  const int TOT = 3 * 3 * 128 * 128;
  if (idx >= TOT) return;
  int j = idx & 7;
  int lane = (idx >> 3) & 63;
  int ct = (idx >> 9) & 7;
  int kwin = (idx >> 12) & 3;
  int p = (idx >> 14) % 3;
  int L = idx / (3 * 16384);
  int k = kwin * 32 + (lane >> 4) * 8 + j;
  int col = ct * 16 + (lane & 15);
  const float* W = (L == 0) ? W0 : ((L == 1) ? W1 : W2);
  float v = W[(p * 128 + k) * 128 + col];
  unsigned short hi, lo;
  bf16split(v, hi, lo);
  WFhi[idx] = hi;
  WFlo[idx] = lo;
}

// ---------------- propagate: out[i] = sum_e norm_e * h[src_e] ----------------

__global__ __launch_bounds__(256) void prop_kernel(const float* __restrict__ h,
                                                   float* __restrict__ out,
                                                   const int* __restrict__ rp,
                                                   const int* __restrict__ ssrc,
                                                   const float* __restrict__ snorm, int N) {
  int node = blockIdx.x * 4 + (threadIdx.x >> 6);
  if (node >= N) return;
  int lane = threadIdx.x & 63;
  int c = lane * 2;
  int e = rp[node], e1 = rp[node + 1];
  float ax0 = 0.f, ay0 = 0.f, ax1 = 0.f, ay1 = 0.f;
  // 8-deep unroll: 8 independent gathers in flight per wave
  for (; e + 7 < e1; e += 8) {
    int s0 = ssrc[e], s1 = ssrc[e + 1], s2 = ssrc[e + 2], s3 = ssrc[e + 3];
    int s4 = ssrc[e + 4], s5 = ssrc[e + 5], s6 = ssrc[e + 6], s7 = ssrc[e + 7];
    float w0 = snorm[e], w1 = snorm[e + 1], w2 = snorm[e + 2], w3 = snorm[e + 3];
    float w4 = snorm[e + 4], w5 = snorm[e + 5], w6 = snorm[e + 6], w7 = snorm[e + 7];
    float2 h0 = *(const float2*)&h[s0 * NCH + c];
    float2 h1 = *(const float2*)&h[s1 * NCH + c];
    float2 h2 = *(const float2*)&h[s2 * NCH + c];
    float2 h3 = *(const float2*)&h[s3 * NCH + c];
    float2 h4 = *(const float2*)&h[s4 * NCH + c];
    float2 h5 = *(const float2*)&h[s5 * NCH + c];
    float2 h6 = *(const float2*)&h[s6 * NCH + c];
    float2 h7 = *(const float2*)&h[s7 * NCH + c];
    ax0 += w0 * h0.x; ay0 += w0 * h0.y;
    ax1 += w1 * h1.x; ay1 += w1 * h1.y;
    ax0 += w2 * h2.x; ay0 += w2 * h2.y;
    ax1 += w3 * h3.x; ay1 += w3 * h3.y;
    ax0 += w4 * h4.x; ay0 += w4 * h4.y;
    ax1 += w5 * h5.x; ay1 += w5 * h5.y;
    ax0 += w6 * h6.x; ay0 += w6 * h6.y;
    ax1 += w7 * h7.x; ay1 += w7 * h7.y;
  }
  for (; e < e1; ++e) {
    int s0 = ssrc[e];
    float w0 = snorm[e];
    float2 h0 = *(const float2*)&h[s0 * NCH + c];
    ax0 += w0 * h0.x; ay0 += w0 * h0.y;
  }
  float2 r; r.x = ax0 + ax1; r.y = ay0 + ay1;
  *(float2*)&out[node * NCH + c] = r;
}

// ------- fused Cheb GEMM via bf16 hi/lo MFMA: out = h@W0 + p1@W1 + (2*p2-h)@W2 + b -------
// out may alias h/p1/p2: each block only reads its own rows (staged before the last
// barrier) and writes those same rows in the epilogue. Blocks own disjoint rows.
__global__ __launch_bounds__(256) void gemm_cheb_mfma(
    const float* h, const float* p1, const float* p2,
    const unsigned short* __restrict__ WFhi,  // this layer: [p][kwin][ct][lane][8]
    const unsigned short* __restrict__ WFlo,
    const float* __restrict__ bias, float* out, int N, int relu) {
  // A in fragment-linear layout: slot = rtile*2+kw (16), then [lane][8]
  __shared__ __align__(16) unsigned short AsHi[16 * 64 * 8];
  __shared__ __align__(16) unsigned short AsLo[16 * 64 * 8];
  int t = threadIdx.x;
  int w = t >> 6, lane = t & 63;
  int rowBase = blockIdx.x * 128;

  f4v acc[2][8];
#pragma unroll
  for (int rt = 0; rt < 2; ++rt)
#pragma unroll
    for (int ct = 0; ct < 8; ++ct) acc[rt][ct] = (f4v)0.f;

  // staging assignment: thread handles row r_st, k-window kw_st, kb = pass
  int r_st = t >> 1;
  int kw_st = t & 1;
  int rt_st = r_st >> 4, rr_st = r_st & 15;

  for (int s = 0; s < 6; ++s) {
    int phase = s >> 1;
    int k0 = (s & 1) * 64;  // k offset within phase
    if (s) __syncthreads();
    // ---- stage A tile (128 rows x 64 k) as hi/lo bf16, fragment-linear ----
    {
      int gRow = rowBase + r_st;
      const float* srcH = h + (size_t)gRow * NCH;
      const float* srcP1 = p1 + (size_t)gRow * NCH;
      const float* srcP2 = p2 + (size_t)gRow * NCH;
#pragma unroll
      for (int pass = 0; pass < 4; ++pass) {
        int gk = k0 + (kw_st * 4 + pass) * 8;
        float v[8];
        if (gRow < N) {
          if (phase == 0) {
            float4 u0 = *(const float4*)&srcH[gk];
            float4 u1 = *(const float4*)&srcH[gk + 4];
            v[0] = u0.x; v[1] = u0.y; v[2] = u0.z; v[3] = u0.w;
            v[4] = u1.x; v[5] = u1.y; v[6] = u1.z; v[7] = u1.w;
          } else if (phase == 1) {
            float4 u0 = *(const float4*)&srcP1[gk];
            float4 u1 = *(const float4*)&srcP1[gk + 4];
            v[0] = u0.x; v[1] = u0.y; v[2] = u0.z; v[3] = u0.w;
            v[4] = u1.x; v[5] = u1.y; v[6] = u1.z; v[7] = u1.w;
          } else {
            float4 a0 = *(const float4*)&srcP2[gk];
            float4 a1 = *(const float4*)&srcP2[gk + 4];
            float4 b0 = *(const float4*)&srcH[gk];
            float4 b1 = *(const float4*)&srcH[gk + 4];
            v[0] = 2.f * a0.x - b0.x; v[1] = 2.f * a0.y - b0.y;
            v[2] = 2.f * a0.z - b0.z; v[3] = 2.f * a0.w - b0.w;
            v[4] = 2.f * a1.x - b1.x; v[5] = 2.f * a1.y - b1.y;
            v[6] = 2.f * a1.z - b1.z; v[7] = 2.f * a1.w - b1.w;
          }
        } else {
#pragma unroll
          for (int j = 0; j < 8; ++j) v[j] = 0.f;
        }
        s8v H, L;
#pragma unroll
        for (int j = 0; j < 8; ++j) {
          unsigned short hi, lo;
          bf16split(v[j], hi, lo);
          H[j] = (short)hi;
          L[j] = (short)lo;
        }
        int slot = rt_st * 2 + kw_st;
        int lidx = rr_st + 16 * pass;  // pass == kb
        int off = (slot * 64 + lidx) * 8;
        *(s8v*)&AsHi[off] = H;
        *(s8v*)&AsLo[off] = L;
      }
    }
    __syncthreads();
    // ---- compute: per wave 2 row-tiles x 8 col-tiles, K=64 (2 windows), 4 hi/lo products ----
    s8v ah[2][2], al[2][2];
#pragma unroll
    for (int rt = 0; rt < 2; ++rt)
#pragma unroll
      for (int kw = 0; kw < 2; ++kw) {
        int slot = (w * 2 + rt) * 2 + kw;
        int off = (slot * 64 + lane) * 8;
        ah[rt][kw] = *(const s8v*)&AsHi[off];
        al[rt][kw] = *(const s8v*)&AsLo[off];
      }
#pragma unroll
    for (int ct = 0; ct < 8; ++ct) {
#pragma unroll
      for (int kw = 0; kw < 2; ++kw) {
        int kwin = (s & 1) * 2 + kw;
        int boff = (phase * 4 + kwin) * 4096 + ct * 512 + lane * 8;
        s8v bh = *(const s8v*)&WFhi[boff];
        s8v bl = *(const s8v*)&WFlo[boff];
#pragma unroll
        for (int rt = 0; rt < 2; ++rt) {
          acc[rt][ct] = __builtin_amdgcn_mfma_f32_16x16x32_bf16(ah[rt][kw], bh, acc[rt][ct], 0, 0, 0);
          acc[rt][ct] = __builtin_amdgcn_mfma_f32_16x16x32_bf16(al[rt][kw], bh, acc[rt][ct], 0, 0, 0);
          acc[rt][ct] = __builtin_amdgcn_mfma_f32_16x16x32_bf16(ah[rt][kw], bl, acc[rt][ct], 0, 0, 0);
          acc[rt][ct] = __builtin_amdgcn_mfma_f32_16x16x32_bf16(al[rt][kw], bl, acc[rt][ct], 0, 0, 0);
        }
      }
    }
  }
  // ---- epilogue: C/D layout col = lane&15, row = (lane>>4)*4 + reg ----
  int crow = (lane >> 4) * 4;
  int ccol = lane & 15;
#pragma unroll
  for (int rt = 0; rt < 2; ++rt) {
    int gRow0 = rowBase + (w * 2 + rt) * 16 + crow;
#pragma unroll
    for (int reg = 0; reg < 4; ++reg) {
      int gRow = gRow0 + reg;
      if (gRow >= N) continue;
#pragma unroll
      for (int ct = 0; ct < 8; ++ct) {
        int col = ct * 16 + ccol;
        float vv = acc[rt][ct][reg] + bias[col];
        if (relu) vv = fmaxf(vv, 0.f);
        out[(size_t)gRow * NCH + col] = vv;
      }
    }
  }
}

// ---------------- pooling + final linear ----------------

__global__ __launch_bounds__(128) void pool_kernel(const float* __restrict__ h,
                                                   const int* __restrict__ batch,
                                                   float* __restrict__ sums,
                                                   float* __restrict__ gcnt, int N) {
  int start = blockIdx.x * POOL_CHUNK;
  if (start >= N) return;
  int end = min(start + POOL_CHUNK, N);
  int c = threadIdx.x;
  float acc = 0.f;
  int cnt = 0;
  int cur = batch[start];
  for (int i = start; i < end; ++i) {
    int g = batch[i];
    if (g != cur) {
      atomicAdd(&sums[cur * NCH + c], acc);
      if (c == 0) atomicAdd(&gcnt[cur], (float)cnt);
      acc = 0.f; cnt = 0; cur = g;
    }
    acc += h[i * NCH + c];
    ++cnt;
  }
  atomicAdd(&sums[cur * NCH + c], acc);
  if (c == 0) atomicAdd(&gcnt[cur], (float)cnt);
}

__global__ void final_kernel(const float* __restrict__ sums, const float* __restrict__ gcnt,
                             const float* __restrict__ lw, const float* __restrict__ lb,
                             float* __restrict__ out) {
  int g = blockIdx.x;
  int o = threadIdx.x;
  if (o >= OUTC) return;
  float inv = 1.0f / fmaxf(gcnt[g], 1.0f);
  float acc = lb[o];
  for (int ch = 0; ch < NCH; ++ch) acc += sums[g * NCH + ch] * inv * lw[ch * OUTC + o];
  out[g * OUTC + o] = acc;
}

// ---------------- launch ----------------

extern "C" void kernel_launch(void* const* d_in, const int* in_sizes, int n_in,
                              void* d_out, int out_size, void* d_ws, size_t ws_size,
                              hipStream_t stream) {
  const float* x  = (const float*)d_in[0];
  const int* ei   = (const int*)d_in[1];
  const int* batch= (const int*)d_in[2];
  const float* W0 = (const float*)d_in[3];
  const float* b0 = (const float*)d_in[4];
  const float* W1 = (const float*)d_in[5];
  const float* b1 = (const float*)d_in[6];
  const float* W2 = (const float*)d_in[7];
  const float* b2 = (const float*)d_in[8];
  const float* lw = (const float*)d_in[9];
  const float* lb = (const float*)d_in[10];
  float* out = (float*)d_out;
  int N = in_sizes[0] / NCH;
  int E = in_sizes[1] / 2;

  char* ws = (char*)d_ws;
  size_t off = 0;
  auto take = [&](size_t bytes) -> char* {
    char* p = ws + off;
    off += (bytes + 511) & ~(size_t)511;
    return p;
  };
  int* sc      = (int*)take((size_t)N * 4);
  int* dc      = (int*)take((size_t)N * 4);
  float* dis   = (float*)take((size_t)N * 4);
  int* rp      = (int*)take((size_t)(N + 1) * 4);
  int* nxt     = (int*)take((size_t)N * 4);
  int* bsum    = (int*)take(1024 * 4);
  int* ssrc    = (int*)take((size_t)E * 4);
  float* snorm = (float*)take((size_t)E * 4);
  float* A     = (float*)take((size_t)N * NCH * 4);
  float* B     = (float*)take((size_t)N * NCH * 4);
  float* D     = (float*)take((size_t)N * NCH * 4);
  unsigned short* WFhi = (unsigned short*)take((size_t)3 * 3 * 128 * 128 * 2);
  unsigned short* WFlo = (unsigned short*)take((size_t)3 * 3 * 128 * 128 * 2);
  float* sums  = (float*)take((size_t)NGRAPHS * NCH * 4);
  float* gcnt  = (float*)take((size_t)NGRAPHS * 4);

  int nb = (N + 1023) / 1024;

  hipMemsetAsync(sc, 0, (size_t)N * 4, stream);
  hipMemsetAsync(dc, 0, (size_t)N * 4, stream);
  hipMemsetAsync(sums, 0, (size_t)NGRAPHS * NCH * 4, stream);
  hipMemsetAsync(gcnt, 0, (size_t)NGRAPHS * 4, stream);

  prep_w_kernel<<<(3 * 3 * 128 * 128 + 255) / 256, 256, 0, stream>>>(W0, W1, W2, WFhi, WFlo);
  hist_kernel<<<(E + 255) / 256, 256, 0, stream>>>(ei, sc, dc, E);
  dis_kernel<<<(N + 255) / 256, 256, 0, stream>>>(sc, dis, N);
  scanA_kernel<<<nb, 256, 0, stream>>>(dc, bsum, N);
  scanB_kernel<<<1, 128, 0, stream>>>(bsum, nb);
  scanC_kernel<<<nb, 256, 0, stream>>>(dc, bsum, rp, nxt, N, E);
  scatter_kernel<<<(E + 255) / 256, 256, 0, stream>>>(ei, dis, nxt, ssrc, snorm, E);

  int pgrid = (N + 3) / 4;
  int ggrid = (N + 127) / 128;
  const int WL = 3 * 4 * 8 * 512;  // shorts per layer in WF layout

  // layer 0
  prop_kernel<<<pgrid, 256, 0, stream>>>(x, A, rp, ssrc, snorm, N);
  prop_kernel<<<pgrid, 256, 0, stream>>>(A, B, rp, ssrc, snorm, N);
  gemm_cheb_mfma<<<ggrid, 256, 0, stream>>>(x, A, B, WFhi + 0 * WL, WFlo + 0 * WL, b0, D, N, 1);
  // layer 1 (out aliases h; safe per kernel comment)
  prop_kernel<<<pgrid, 256, 0, stream>>>(D, A, rp, ssrc, snorm, N);
  prop_kernel<<<pgrid, 256, 0, stream>>>(A, B, rp, ssrc, snorm, N);
  gemm_cheb_mfma<<<ggrid, 256, 0, stream>>>(D, A, B, WFhi + 1 * WL, WFlo + 1 * WL, b1, D, N, 1);
  // layer 2
  prop_kernel<<<pgrid, 256, 0, stream>>>(D, A, rp, ssrc, snorm, N);
  prop_kernel<<<pgrid, 256, 0, stream>>>(A, B, rp, ssrc, snorm, N);
  gemm_cheb_mfma<<<ggrid, 256, 0, stream>>>(D, A, B, WFhi + 2 * WL, WFlo + 2 * WL, b2, D, N, 0);

  pool_kernel<<<(N + POOL_CHUNK - 1) / POOL_CHUNK, 128, 0, stream>>>(D, batch, sums, gcnt, N);
  final_kernel<<<NGRAPHS, 16, 0, stream>>>(sums, gcnt, lw, lb, out);
}

// Round 5
// 1086.113 us; speedup vs baseline: 1.3722x; 1.2545x over previous
//
#include <hip/hip_runtime.h>
#include <hip/hip_fp16.h>
#include <cstdint>

#define NCH 128
#define NGRAPHS 64
#define OUTC 10
#define POOL_CHUNK 256

typedef __attribute__((ext_vector_type(8))) short s8v;
typedef __attribute__((ext_vector_type(4))) float f4v;

// float -> bf16(hi) + bf16(lo), RNE. a ~= hi + lo to ~2^-18 rel (exact for fp16 inputs).
__device__ __forceinline__ void bf16split(float a, unsigned short& hi, unsigned short& lo) {
  union { float f; unsigned u; } x; x.f = a;
  unsigned r = x.u + 0x7fffu + ((x.u >> 16) & 1u);
  hi = (unsigned short)(r >> 16);
  union { unsigned u; float f; } hf; hf.u = ((unsigned)hi) << 16;
  float res = a - hf.f;               // exact (Sterbenz)
  union { float f; unsigned u; } y; y.f = res;
  unsigned r2 = y.u + 0x7fffu + ((y.u >> 16) & 1u);
  lo = (unsigned short)(r2 >> 16);
}

// ---------------- preprocessing ----------------

__global__ __launch_bounds__(256) void hist_kernel(const int* __restrict__ ei,
                                                   int* __restrict__ sc,
                                                   int* __restrict__ dc, int E) {
  int i = blockIdx.x * 256 + threadIdx.x;
  if (i >= E) return;
  atomicAdd(&sc[ei[i]], 1);
  atomicAdd(&dc[ei[E + i]], 1);
}

__global__ __launch_bounds__(256) void dis_kernel(const int* __restrict__ sc,
                                                  float* __restrict__ dis, int N) {
  int i = blockIdx.x * 256 + threadIdx.x;
  if (i < N) {
    int d = sc[i];
    dis[i] = d > 0 ? rsqrtf((float)d) : 0.0f;
  }
}

__global__ __launch_bounds__(256) void f2h_kernel(const float* __restrict__ in,
                                                  __half* __restrict__ out, int n) {
  int i = (blockIdx.x * 256 + threadIdx.x) * 4;
  if (i + 3 < n) {
    float4 v = *(const float4*)&in[i];
    __half2 a = __float22half2_rn(make_float2(v.x, v.y));
    __half2 b = __float22half2_rn(make_float2(v.z, v.w));
    *(__half2*)&out[i] = a;
    *(__half2*)&out[i + 2] = b;
  } else {
    for (; i < n; ++i) out[i] = __float2half(in[i]);
  }
}

__global__ __launch_bounds__(256) void scanA_kernel(const int* __restrict__ cnt,
                                                    int* __restrict__ bsum, int N) {
  __shared__ int wred[4];
  int t = threadIdx.x;
  int idx = blockIdx.x * 1024 + t * 4;
  int s = 0;
#pragma unroll
  for (int j = 0; j < 4; ++j)
    if (idx + j < N) s += cnt[idx + j];
  for (int d = 32; d; d >>= 1) s += __shfl_down(s, d);
  if ((t & 63) == 0) wred[t >> 6] = s;
  __syncthreads();
  if (t == 0) bsum[blockIdx.x] = wred[0] + wred[1] + wred[2] + wred[3];
}

__global__ void scanB_kernel(int* __restrict__ bsum, int nb) {
  __shared__ int wtot[2];
  __shared__ int carry_s;
  int t = threadIdx.x;  // 128 threads
  if (t == 0) carry_s = 0;
  __syncthreads();
  for (int base = 0; base < nb; base += 128) {
    int i = base + t;
    int v = (i < nb) ? bsum[i] : 0;
    int lane = t & 63, w = t >> 6;
    int ps = v;
    for (int d = 1; d < 64; d <<= 1) {
      int o = __shfl_up(ps, d);
      if (lane >= d) ps += o;
    }
    if (lane == 63) wtot[w] = ps;
    __syncthreads();
    int excl = ps - v + (w ? wtot[0] : 0) + carry_s;
    if (i < nb) bsum[i] = excl;
    __syncthreads();
    if (t == 0) carry_s += wtot[0] + wtot[1];
    __syncthreads();
  }
}

__global__ __launch_bounds__(256) void scanC_kernel(const int* __restrict__ cnt,
                                                    const int* __restrict__ bsum,
                                                    int* __restrict__ rp,
                                                    int* __restrict__ nxt, int N, int E) {
  __shared__ int wsum[4];
  int t = threadIdx.x;
  int idx = blockIdx.x * 1024 + t * 4;
  int v[4];
#pragma unroll
  for (int j = 0; j < 4; ++j) v[j] = (idx + j < N) ? cnt[idx + j] : 0;
  int s = v[0] + v[1] + v[2] + v[3];
  int lane = t & 63, w = t >> 6;
  int ps = s;
  for (int d = 1; d < 64; d <<= 1) {
    int o = __shfl_up(ps, d);
    if (lane >= d) ps += o;
  }
  if (lane == 63) wsum[w] = ps;
  __syncthreads();
  int woff = 0;
  for (int i = 0; i < w; ++i) woff += wsum[i];
  int off = bsum[blockIdx.x] + woff + ps - s;
#pragma unroll
  for (int j = 0; j < 4; ++j) {
    if (idx + j < N) {
      rp[idx + j] = off;
      nxt[idx + j] = off;
      off += v[j];
    }
  }
  if (blockIdx.x == 0 && t == 0) rp[N] = E;
}

__global__ __launch_bounds__(256) void scatter_kernel(const int* __restrict__ ei,
                                                      const float* __restrict__ dis,
                                                      int* __restrict__ nxt,
                                                      int2* __restrict__ sedge, int E) {
  int i = blockIdx.x * 256 + threadIdx.x;
  if (i >= E) return;
  int s = ei[i];
  int d = ei[E + i];
  int pos = atomicAdd(&nxt[d], 1);
  sedge[pos] = make_int2(s, __float_as_int(-dis[s] * dis[d]));
}

// --- weight prep: transpose + bf16 hi/lo split into MFMA-fragment-linear layout ---
// Per layer L, phase p: [kwin 0..3][ct 0..7][lane 0..63][j 0..7]
// element = W_L[p][k][col], k = kwin*32 + (lane>>4)*8 + j, col = ct*16 + (lane&15)
__global__ __launch_bounds__(256) void prep_w_kernel(const float* __restrict__ W0,
                                                     const float* __restrict__ W1,
                                                     const float* __restrict__ W2,
                                                     unsigned short* __restrict__ WFhi,
                                                     unsigned short* __restrict__ WFlo) {
  int idx = blockIdx.x * 256 + threadIdx.x;
  const int TOT = 3 * 3 * 128 * 128;
  if (idx >= TOT) return;
  int j = idx & 7;
  int lane = (idx >> 3) & 63;
  int ct = (idx >> 9) & 7;
  int kwin = (idx >> 12) & 3;
  int p = (idx >> 14) % 3;
  int L = idx / (3 * 16384);
  int k = kwin * 32 + (lane >> 4) * 8 + j;
  int col = ct * 16 + (lane & 15);
  const float* W = (L == 0) ? W0 : ((L == 1) ? W1 : W2);
  float v = W[(p * 128 + k) * 128 + col];
  unsigned short hi, lo;
  bf16split(v, hi, lo);
  WFhi[idx] = hi;
  WFlo[idx] = lo;
}

// ---------------- propagate (fp16 operand): out[i] = sum_e norm_e * h[src_e] ----------------

__global__ __launch_bounds__(256) void prop_kernel(const __half* __restrict__ h,
                                                   __half* __restrict__ out,
                                                   const int* __restrict__ rp,
                                                   const int2* __restrict__ sedge, int N) {
  int node = blockIdx.x * 4 + (threadIdx.x >> 6);
  if (node >= N) return;
  int lane = threadIdx.x & 63;
  int c = lane * 2;
  int e = rp[node], e1 = rp[node + 1];
  float ax0 = 0.f, ay0 = 0.f, ax1 = 0.f, ay1 = 0.f;
  // 8-deep unroll: 8 independent gathers in flight per wave
  for (; e + 7 < e1; e += 8) {
    int2 E0 = sedge[e], E1 = sedge[e + 1], E2 = sedge[e + 2], E3 = sedge[e + 3];
    int2 E4 = sedge[e + 4], E5 = sedge[e + 5], E6 = sedge[e + 6], E7 = sedge[e + 7];
    float2 h0 = __half22float2(*(const __half2*)&h[(size_t)E0.x * NCH + c]);
    float2 h1 = __half22float2(*(const __half2*)&h[(size_t)E1.x * NCH + c]);
    float2 h2 = __half22float2(*(const __half2*)&h[(size_t)E2.x * NCH + c]);
    float2 h3 = __half22float2(*(const __half2*)&h[(size_t)E3.x * NCH + c]);
    float2 h4 = __half22float2(*(const __half2*)&h[(size_t)E4.x * NCH + c]);
    float2 h5 = __half22float2(*(const __half2*)&h[(size_t)E5.x * NCH + c]);
    float2 h6 = __half22float2(*(const __half2*)&h[(size_t)E6.x * NCH + c]);
    float2 h7 = __half22float2(*(const __half2*)&h[(size_t)E7.x * NCH + c]);
    float w0 = __int_as_float(E0.y), w1 = __int_as_float(E1.y);
    float w2 = __int_as_float(E2.y), w3 = __int_as_float(E3.y);
    float w4 = __int_as_float(E4.y), w5 = __int_as_float(E5.y);
    float w6 = __int_as_float(E6.y), w7 = __int_as_float(E7.y);
    ax0 += w0 * h0.x; ay0 += w0 * h0.y;
    ax1 += w1 * h1.x; ay1 += w1 * h1.y;
    ax0 += w2 * h2.x; ay0 += w2 * h2.y;
    ax1 += w3 * h3.x; ay1 += w3 * h3.y;
    ax0 += w4 * h4.x; ay0 += w4 * h4.y;
    ax1 += w5 * h5.x; ay1 += w5 * h5.y;
    ax0 += w6 * h6.x; ay0 += w6 * h6.y;
    ax1 += w7 * h7.x; ay1 += w7 * h7.y;
  }
  for (; e < e1; ++e) {
    int2 E0 = sedge[e];
    float w0 = __int_as_float(E0.y);
    float2 h0 = __half22float2(*(const __half2*)&h[(size_t)E0.x * NCH + c]);
    ax0 += w0 * h0.x; ay0 += w0 * h0.y;
  }
  __half2 r = __float22half2_rn(make_float2(ax0 + ax1, ay0 + ay1));
  *(__half2*)&out[(size_t)node * NCH + c] = r;
}

// ------- fused Cheb GEMM via bf16 hi/lo MFMA: out = h@W0 + p1@W1 + (2*p2-h)@W2 + b -------
// h is fp32; p1,p2 are fp16. out may alias h: each block only reads its own rows
// (staged before the last barrier) and writes those rows after it; blocks own disjoint rows.
__global__ __launch_bounds__(256) void gemm_cheb_mfma(
    const float* h, const __half* __restrict__ p1, const __half* __restrict__ p2,
    const unsigned short* __restrict__ WFhi,  // this layer: [p][kwin][ct][lane][8]
    const unsigned short* __restrict__ WFlo,
    const float* __restrict__ bias, float* out, __half* out16, int N, int relu) {
  __shared__ __align__(16) unsigned short AsHi[16 * 64 * 8];
  __shared__ __align__(16) unsigned short AsLo[16 * 64 * 8];
  int t = threadIdx.x;
  int w = t >> 6, lane = t & 63;
  int rowBase = blockIdx.x * 128;

  f4v acc[2][8];
#pragma unroll
  for (int rt = 0; rt < 2; ++rt)
#pragma unroll
    for (int ct = 0; ct < 8; ++ct) acc[rt][ct] = (f4v)0.f;

  int r_st = t >> 1;
  int kw_st = t & 1;
  int rt_st = r_st >> 4, rr_st = r_st & 15;

  for (int s = 0; s < 6; ++s) {
    int phase = s >> 1;
    int k0 = (s & 1) * 64;
    if (s) __syncthreads();
    // ---- stage A tile (128 rows x 64 k) as hi/lo bf16, fragment-linear ----
    {
      int gRow = rowBase + r_st;
      const float* srcH = h + (size_t)gRow * NCH;
      const __half* srcP1 = p1 + (size_t)gRow * NCH;
      const __half* srcP2 = p2 + (size_t)gRow * NCH;
#pragma unroll
      for (int pass = 0; pass < 4; ++pass) {
        int gk = k0 + (kw_st * 4 + pass) * 8;
        float v[8];
        if (gRow < N) {
          if (phase == 0) {
            float4 u0 = *(const float4*)&srcH[gk];
            float4 u1 = *(const float4*)&srcH[gk + 4];
            v[0] = u0.x; v[1] = u0.y; v[2] = u0.z; v[3] = u0.w;
            v[4] = u1.x; v[5] = u1.y; v[6] = u1.z; v[7] = u1.w;
          } else if (phase == 1) {
            union { s8v v; __half h[8]; } u;
            u.v = *(const s8v*)&srcP1[gk];
#pragma unroll
            for (int j = 0; j < 8; ++j) v[j] = __half2float(u.h[j]);
          } else {
            union { s8v v; __half h[8]; } u;
            u.v = *(const s8v*)&srcP2[gk];
            float4 b0 = *(const float4*)&srcH[gk];
            float4 b1 = *(const float4*)&srcH[gk + 4];
            float bb[8] = {b0.x, b0.y, b0.z, b0.w, b1.x, b1.y, b1.z, b1.w};
#pragma unroll
            for (int j = 0; j < 8; ++j) v[j] = 2.f * __half2float(u.h[j]) - bb[j];
          }
        } else {
#pragma unroll
          for (int j = 0; j < 8; ++j) v[j] = 0.f;
        }
        s8v H, L;
#pragma unroll
        for (int j = 0; j < 8; ++j) {
          unsigned short hi, lo;
          bf16split(v[j], hi, lo);
          H[j] = (short)hi;
          L[j] = (short)lo;
        }
        int slot = rt_st * 2 + kw_st;
        int lidx = rr_st + 16 * pass;
        int off = (slot * 64 + lidx) * 8;
        *(s8v*)&AsHi[off] = H;
        *(s8v*)&AsLo[off] = L;
      }
    }
    __syncthreads();
    // ---- compute: per wave 2 row-tiles x 8 col-tiles, K=64, 3 hi/lo products ----
    s8v ah[2][2], al[2][2];
#pragma unroll
    for (int rt = 0; rt < 2; ++rt)
#pragma unroll
      for (int kw = 0; kw < 2; ++kw) {
        int slot = (w * 2 + rt) * 2 + kw;
        int off = (slot * 64 + lane) * 8;
        ah[rt][kw] = *(const s8v*)&AsHi[off];
        al[rt][kw] = *(const s8v*)&AsLo[off];
      }
#pragma unroll
    for (int ct = 0; ct < 8; ++ct) {
#pragma unroll
      for (int kw = 0; kw < 2; ++kw) {
        int kwin = (s & 1) * 2 + kw;
        int boff = (phase * 4 + kwin) * 4096 + ct * 512 + lane * 8;
        s8v bh = *(const s8v*)&WFhi[boff];
        s8v bl = *(const s8v*)&WFlo[boff];
#pragma unroll
        for (int rt = 0; rt < 2; ++rt) {
          acc[rt][ct] = __builtin_amdgcn_mfma_f32_16x16x32_bf16(ah[rt][kw], bh, acc[rt][ct], 0, 0, 0);
          acc[rt][ct] = __builtin_amdgcn_mfma_f32_16x16x32_bf16(al[rt][kw], bh, acc[rt][ct], 0, 0, 0);
          acc[rt][ct] = __builtin_amdgcn_mfma_f32_16x16x32_bf16(ah[rt][kw], bl, acc[rt][ct], 0, 0, 0);
          // lo*lo dropped: contributes ~2^-16 relative
        }
      }
    }
  }
  // ---- epilogue: C/D layout col = lane&15, row = (lane>>4)*4 + reg ----
  int crow = (lane >> 4) * 4;
  int ccol = lane & 15;
#pragma unroll
  for (int rt = 0; rt < 2; ++rt) {
    int gRow0 = rowBase + (w * 2 + rt) * 16 + crow;
#pragma unroll
    for (int reg = 0; reg < 4; ++reg) {
      int gRow = gRow0 + reg;
      if (gRow >= N) continue;
#pragma unroll
      for (int ct = 0; ct < 8; ++ct) {
        int col = ct * 16 + ccol;
        float vv = acc[rt][ct][reg] + bias[col];
        if (relu) vv = fmaxf(vv, 0.f);
        out[(size_t)gRow * NCH + col] = vv;
        if (out16) out16[(size_t)gRow * NCH + col] = __float2half(vv);
      }
    }
  }
}

// ---------------- pooling + final linear ----------------

__global__ __launch_bounds__(128) void pool_kernel(const float* __restrict__ h,
                                                   const int* __restrict__ batch,
                                                   float* __restrict__ sums,
                                                   float* __restrict__ gcnt, int N) {
  int start = blockIdx.x * POOL_CHUNK;
  if (start >= N) return;
  int end = min(start + POOL_CHUNK, N);
  int c = threadIdx.x;
  float acc = 0.f;
  int cnt = 0;
  int cur = batch[start];
  for (int i = start; i < end; ++i) {
    int g = batch[i];
    if (g != cur) {
      atomicAdd(&sums[cur * NCH + c], acc);
      if (c == 0) atomicAdd(&gcnt[cur], (float)cnt);
      acc = 0.f; cnt = 0; cur = g;
    }
    acc += h[i * NCH + c];
    ++cnt;
  }
  atomicAdd(&sums[cur * NCH + c], acc);
  if (c == 0) atomicAdd(&gcnt[cur], (float)cnt);
}

__global__ void final_kernel(const float* __restrict__ sums, const float* __restrict__ gcnt,
                             const float* __restrict__ lw, const float* __restrict__ lb,
                             float* __restrict__ out) {
  int g = blockIdx.x;
  int o = threadIdx.x;
  if (o >= OUTC) return;
  float inv = 1.0f / fmaxf(gcnt[g], 1.0f);
  float acc = lb[o];
  for (int ch = 0; ch < NCH; ++ch) acc += sums[g * NCH + ch] * inv * lw[ch * OUTC + o];
  out[g * OUTC + o] = acc;
}

// ---------------- launch ----------------

extern "C" void kernel_launch(void* const* d_in, const int* in_sizes, int n_in,
                              void* d_out, int out_size, void* d_ws, size_t ws_size,
                              hipStream_t stream) {
  const float* x  = (const float*)d_in[0];
  const int* ei   = (const int*)d_in[1];
  const int* batch= (const int*)d_in[2];
  const float* W0 = (const float*)d_in[3];
  const float* b0 = (const float*)d_in[4];
  const float* W1 = (const float*)d_in[5];
  const float* b1 = (const float*)d_in[6];
  const float* W2 = (const float*)d_in[7];
  const float* b2 = (const float*)d_in[8];
  const float* lw = (const float*)d_in[9];
  const float* lb = (const float*)d_in[10];
  float* out = (float*)d_out;
  int N = in_sizes[0] / NCH;
  int E = in_sizes[1] / 2;

  char* ws = (char*)d_ws;
  size_t off = 0;
  auto take = [&](size_t bytes) -> char* {
    char* p = ws + off;
    off += (bytes + 511) & ~(size_t)511;
    return p;
  };
  int* sc      = (int*)take((size_t)N * 4);
  int* dc      = (int*)take((size_t)N * 4);
  float* dis   = (float*)take((size_t)N * 4);
  int* rp      = (int*)take((size_t)(N + 1) * 4);
  int* nxt     = (int*)take((size_t)N * 4);
  int* bsum    = (int*)take(1024 * 4);
  int2* sedge  = (int2*)take((size_t)E * 8);
  float* D     = (float*)take((size_t)N * NCH * 4);    // fp32 h for GEMM/pool
  __half* x16  = (__half*)take((size_t)N * NCH * 2);
  __half* H16  = (__half*)take((size_t)N * NCH * 2);
  __half* P1h  = (__half*)take((size_t)N * NCH * 2);
  __half* P2h  = (__half*)take((size_t)N * NCH * 2);
  unsigned short* WFhi = (unsigned short*)take((size_t)3 * 3 * 128 * 128 * 2);
  unsigned short* WFlo = (unsigned short*)take((size_t)3 * 3 * 128 * 128 * 2);
  float* sums  = (float*)take((size_t)NGRAPHS * NCH * 4);
  float* gcnt  = (float*)take((size_t)NGRAPHS * 4);

  int nb = (N + 1023) / 1024;

  hipMemsetAsync(sc, 0, (size_t)N * 4, stream);
  hipMemsetAsync(dc, 0, (size_t)N * 4, stream);
  hipMemsetAsync(sums, 0, (size_t)NGRAPHS * NCH * 4, stream);
  hipMemsetAsync(gcnt, 0, (size_t)NGRAPHS * 4, stream);

  prep_w_kernel<<<(3 * 3 * 128 * 128 + 255) / 256, 256, 0, stream>>>(W0, W1, W2, WFhi, WFlo);
  f2h_kernel<<<(N * NCH / 4 + 255) / 256, 256, 0, stream>>>(x, x16, N * NCH);
  hist_kernel<<<(E + 255) / 256, 256, 0, stream>>>(ei, sc, dc, E);
  dis_kernel<<<(N + 255) / 256, 256, 0, stream>>>(sc, dis, N);
  scanA_kernel<<<nb, 256, 0, stream>>>(dc, bsum, N);
  scanB_kernel<<<1, 128, 0, stream>>>(bsum, nb);
  scanC_kernel<<<nb, 256, 0, stream>>>(dc, bsum, rp, nxt, N, E);
  scatter_kernel<<<(E + 255) / 256, 256, 0, stream>>>(ei, dis, nxt, sedge, E);

  int pgrid = (N + 3) / 4;
  int ggrid = (N + 127) / 128;
  const int WL = 3 * 4 * 8 * 512;  // shorts per layer in WF layout

  // layer 0
  prop_kernel<<<pgrid, 256, 0, stream>>>(x16, P1h, rp, sedge, N);
  prop_kernel<<<pgrid, 256, 0, stream>>>(P1h, P2h, rp, sedge, N);
  gemm_cheb_mfma<<<ggrid, 256, 0, stream>>>(x, P1h, P2h, WFhi + 0 * WL, WFlo + 0 * WL, b0, D, H16, N, 1);
  // layer 1 (out aliases h; safe per kernel comment)
  prop_kernel<<<pgrid, 256, 0, stream>>>(H16, P1h, rp, sedge, N);
  prop_kernel<<<pgrid, 256, 0, stream>>>(P1h, P2h, rp, sedge, N);
  gemm_cheb_mfma<<<ggrid, 256, 0, stream>>>(D, P1h, P2h, WFhi + 1 * WL, WFlo + 1 * WL, b1, D, H16, N, 1);
  // layer 2
  prop_kernel<<<pgrid, 256, 0, stream>>>(H16, P1h, rp, sedge, N);
  prop_kernel<<<pgrid, 256, 0, stream>>>(P1h, P2h, rp, sedge, N);
  gemm_cheb_mfma<<<ggrid, 256, 0, stream>>>(D, P1h, P2h, WFhi + 2 * WL, WFlo + 2 * WL, b2, D, (__half*)nullptr, N, 0);

  pool_kernel<<<(N + POOL_CHUNK - 1) / POOL_CHUNK, 128, 0, stream>>>(D, batch, sums, gcnt, N);
  final_kernel<<<NGRAPHS, 16, 0, stream>>>(sums, gcnt, lw, lb, out);
}

// Round 6
// 975.709 us; speedup vs baseline: 1.5275x; 1.1132x over previous
//
#include <hip/hip_runtime.h>
#include <hip/hip_fp16.h>
#include <cstdint>

#define NCH 128
#define NGRAPHS 64
#define OUTC 10
#define POOL_CHUNK 256

typedef __attribute__((ext_vector_type(8))) short s8v;
typedef __attribute__((ext_vector_type(8))) _Float16 h8v;
typedef __attribute__((ext_vector_type(4))) float f4v;

// ---------------- preprocessing ----------------

// fused: src-degree histogram + dst count + per-edge rank within dst bucket
__global__ __launch_bounds__(256) void rank_hist_kernel(const int* __restrict__ ei,
                                                        int* __restrict__ sc,
                                                        int* __restrict__ dc,
                                                        int* __restrict__ rank, int E) {
  int i = blockIdx.x * 256 + threadIdx.x;
  if (i >= E) return;
  atomicAdd(&sc[ei[i]], 1);
  rank[i] = atomicAdd(&dc[ei[E + i]], 1);
}

__global__ __launch_bounds__(256) void dis_kernel(const int* __restrict__ sc,
                                                  float* __restrict__ dis, int N) {
  int i = blockIdx.x * 256 + threadIdx.x;
  if (i < N) {
    int d = sc[i];
    dis[i] = d > 0 ? rsqrtf((float)d) : 0.0f;
  }
}

__global__ __launch_bounds__(256) void f2h_kernel(const float* __restrict__ in,
                                                  __half* __restrict__ out, int n) {
  int i = (blockIdx.x * 256 + threadIdx.x) * 4;
  if (i + 3 < n) {
    float4 v = *(const float4*)&in[i];
    __half2 a = __float22half2_rn(make_float2(v.x, v.y));
    __half2 b = __float22half2_rn(make_float2(v.z, v.w));
    *(__half2*)&out[i] = a;
    *(__half2*)&out[i + 2] = b;
  } else {
    for (; i < n; ++i) out[i] = __float2half(in[i]);
  }
}

__global__ __launch_bounds__(256) void scanA_kernel(const int* __restrict__ cnt,
                                                    int* __restrict__ bsum, int N) {
  __shared__ int wred[4];
  int t = threadIdx.x;
  int idx = blockIdx.x * 1024 + t * 4;
  int s = 0;
#pragma unroll
  for (int j = 0; j < 4; ++j)
    if (idx + j < N) s += cnt[idx + j];
  for (int d = 32; d; d >>= 1) s += __shfl_down(s, d);
  if ((t & 63) == 0) wred[t >> 6] = s;
  __syncthreads();
  if (t == 0) bsum[blockIdx.x] = wred[0] + wred[1] + wred[2] + wred[3];
}

__global__ void scanB_kernel(int* __restrict__ bsum, int nb) {
  __shared__ int wtot[2];
  __shared__ int carry_s;
  int t = threadIdx.x;  // 128 threads
  if (t == 0) carry_s = 0;
  __syncthreads();
  for (int base = 0; base < nb; base += 128) {
    int i = base + t;
    int v = (i < nb) ? bsum[i] : 0;
    int lane = t & 63, w = t >> 6;
    int ps = v;
    for (int d = 1; d < 64; d <<= 1) {
      int o = __shfl_up(ps, d);
      if (lane >= d) ps += o;
    }
    if (lane == 63) wtot[w] = ps;
    __syncthreads();
    int excl = ps - v + (w ? wtot[0] : 0) + carry_s;
    if (i < nb) bsum[i] = excl;
    __syncthreads();
    if (t == 0) carry_s += wtot[0] + wtot[1];
    __syncthreads();
  }
}

__global__ __launch_bounds__(256) void scanC_kernel(const int* __restrict__ cnt,
                                                    const int* __restrict__ bsum,
                                                    int* __restrict__ rp, int N, int E) {
  __shared__ int wsum[4];
  int t = threadIdx.x;
  int idx = blockIdx.x * 1024 + t * 4;
  int v[4];
#pragma unroll
  for (int j = 0; j < 4; ++j) v[j] = (idx + j < N) ? cnt[idx + j] : 0;
  int s = v[0] + v[1] + v[2] + v[3];
  int lane = t & 63, w = t >> 6;
  int ps = s;
  for (int d = 1; d < 64; d <<= 1) {
    int o = __shfl_up(ps, d);
    if (lane >= d) ps += o;
  }
  if (lane == 63) wsum[w] = ps;
  __syncthreads();
  int woff = 0;
  for (int i = 0; i < w; ++i) woff += wsum[i];
  int off = bsum[blockIdx.x] + woff + ps - s;
#pragma unroll
  for (int j = 0; j < 4; ++j) {
    if (idx + j < N) {
      rp[idx + j] = off;
      off += v[j];
    }
  }
  if (blockIdx.x == 0 && t == 0) rp[N] = E;
}

// atomic-free scatter: position = rp[dst] + rank[edge]
__global__ __launch_bounds__(256) void scatter_kernel(const int* __restrict__ ei,
                                                      const float* __restrict__ dis,
                                                      const int* __restrict__ rp,
                                                      const int* __restrict__ rank,
                                                      int2* __restrict__ sedge, int E) {
  int i = blockIdx.x * 256 + threadIdx.x;
  if (i >= E) return;
  int s = ei[i];
  int d = ei[E + i];
  sedge[rp[d] + rank[i]] = make_int2(s, __float_as_int(-dis[s] * dis[d]));
}

// --- weight prep: transpose + fp16 hi/lo(x2^11) split into MFMA-fragment-linear layout ---
// Per layer L, phase p: [kwin 0..3][ct 0..7][lane 0..63][j 0..7]
// element = W_L[p][k][col], k = kwin*32 + (lane>>4)*8 + j, col = ct*16 + (lane&15)
__global__ __launch_bounds__(256) void prep_w_kernel(const float* __restrict__ W0,
                                                     const float* __restrict__ W1,
                                                     const float* __restrict__ W2,
                                                     __half* __restrict__ WFhi,
                                                     __half* __restrict__ WFlo) {
  int idx = blockIdx.x * 256 + threadIdx.x;
  const int TOT = 3 * 3 * 128 * 128;
  if (idx >= TOT) return;
  int j = idx & 7;
  int lane = (idx >> 3) & 63;
  int ct = (idx >> 9) & 7;
  int kwin = (idx >> 12) & 3;
  int p = (idx >> 14) % 3;
  int L = idx / (3 * 16384);
  int k = kwin * 32 + (lane >> 4) * 8 + j;
  int col = ct * 16 + (lane & 15);
  const float* W = (L == 0) ? W0 : ((L == 1) ? W1 : W2);
  float v = W[(p * 128 + k) * 128 + col];
  __half hi = __float2half_rn(v);
  float resid = v - __half2float(hi);
  __half lo = __float2half_rn(resid * 2048.0f);  // scaled to stay normal in fp16
  WFhi[idx] = hi;
  WFlo[idx] = lo;
}

// ---------------- propagate (fp16 operand): out[i] = sum_e norm_e * h[src_e] ----------------

__global__ __launch_bounds__(256) void prop_kernel(const __half* __restrict__ h,
                                                   __half* __restrict__ out,
                                                   const int* __restrict__ rp,
                                                   const int2* __restrict__ sedge, int N) {
  int node = blockIdx.x * 4 + (threadIdx.x >> 6);
  if (node >= N) return;
  int lane = threadIdx.x & 63;
  int c = lane * 2;
  int e = rp[node], e1 = rp[node + 1];
  float ax0 = 0.f, ay0 = 0.f, ax1 = 0.f, ay1 = 0.f;
  for (; e + 7 < e1; e += 8) {
    int2 E0 = sedge[e], E1 = sedge[e + 1], E2 = sedge[e + 2], E3 = sedge[e + 3];
    int2 E4 = sedge[e + 4], E5 = sedge[e + 5], E6 = sedge[e + 6], E7 = sedge[e + 7];
    float2 h0 = __half22float2(*(const __half2*)&h[(size_t)E0.x * NCH + c]);
    float2 h1 = __half22float2(*(const __half2*)&h[(size_t)E1.x * NCH + c]);
    float2 h2 = __half22float2(*(const __half2*)&h[(size_t)E2.x * NCH + c]);
    float2 h3 = __half22float2(*(const __half2*)&h[(size_t)E3.x * NCH + c]);
    float2 h4 = __half22float2(*(const __half2*)&h[(size_t)E4.x * NCH + c]);
    float2 h5 = __half22float2(*(const __half2*)&h[(size_t)E5.x * NCH + c]);
    float2 h6 = __half22float2(*(const __half2*)&h[(size_t)E6.x * NCH + c]);
    float2 h7 = __half22float2(*(const __half2*)&h[(size_t)E7.x * NCH + c]);
    float w0 = __int_as_float(E0.y), w1 = __int_as_float(E1.y);
    float w2 = __int_as_float(E2.y), w3 = __int_as_float(E3.y);
    float w4 = __int_as_float(E4.y), w5 = __int_as_float(E5.y);
    float w6 = __int_as_float(E6.y), w7 = __int_as_float(E7.y);
    ax0 += w0 * h0.x; ay0 += w0 * h0.y;
    ax1 += w1 * h1.x; ay1 += w1 * h1.y;
    ax0 += w2 * h2.x; ay0 += w2 * h2.y;
    ax1 += w3 * h3.x; ay1 += w3 * h3.y;
    ax0 += w4 * h4.x; ay0 += w4 * h4.y;
    ax1 += w5 * h5.x; ay1 += w5 * h5.y;
    ax0 += w6 * h6.x; ay0 += w6 * h6.y;
    ax1 += w7 * h7.x; ay1 += w7 * h7.y;
  }
  for (; e < e1; ++e) {
    int2 E0 = sedge[e];
    float w0 = __int_as_float(E0.y);
    float2 h0 = __half22float2(*(const __half2*)&h[(size_t)E0.x * NCH + c]);
    ax0 += w0 * h0.x; ay0 += w0 * h0.y;
  }
  __half2 r = __float22half2_rn(make_float2(ax0 + ax1, ay0 + ay1));
  *(__half2*)&out[(size_t)node * NCH + c] = r;
}

// ------- fused Cheb GEMM via native f16 MFMA: out = h@W0 + p1@W1 + (2*p2-h)@W2 + b -------
// All activations fp16 (A fragments exact in f16 MFMA). W = Whi + Wlo/2048 via dual
// fp32 accumulators. out may alias h: each block reads only its own rows (before the
// final barrier) and writes those rows in the epilogue; blocks own disjoint rows.
__global__ __launch_bounds__(256) void gemm_cheb_mfma(
    const __half* h, const __half* p1, const __half* p2,
    const __half* __restrict__ WFhi,  // this layer: [p][kwin][ct][lane][8]
    const __half* __restrict__ WFlo,
    const float* __restrict__ bias, __half* out, int N, int relu) {
  // 1024 chunks of 16B, chunk g = slot*64 + lidx; slot=(wv*2+rt)*2+kw, lidx = rr + 16*kb
  __shared__ __align__(16) __half As[1024 * 8];
  int t = threadIdx.x;
  int w = t >> 6, lane = t & 63;
  int rowBase = blockIdx.x * 128;

  f4v accH[2][8], accL[2][8];
#pragma unroll
  for (int rt = 0; rt < 2; ++rt)
#pragma unroll
    for (int ct = 0; ct < 8; ++ct) { accH[rt][ct] = (f4v)0.f; accL[rt][ct] = (f4v)0.f; }

  // staging: thread t, pass p writes chunk g = p*256 + t (wave-contiguous -> conflict-free)
  // chunk g holds row = tile16(slot)*16 + (lidx&15), k-chunk kc = (slot&1)*4 + (lidx>>4)
  int pre_row[4], pre_kc[4];
#pragma unroll
  for (int p = 0; p < 4; ++p) {
    int g = p * 256 + t;
    int slot = g >> 6, lidx = g & 63;
    pre_row[p] = (slot >> 2) * 32 + ((slot >> 1) & 1) * 16 + (lidx & 15);
    pre_kc[p] = (slot & 1) * 4 + (lidx >> 4);
  }

  for (int s = 0; s < 6; ++s) {
    int phase = s >> 1;
    int k0 = (s & 1) * 64;
    if (s) __syncthreads();
#pragma unroll
    for (int p = 0; p < 4; ++p) {
      int gRow = rowBase + pre_row[p];
      int gR = min(gRow, N - 1);  // clamp: avoids OOB, garbage rows never stored
      int gk = k0 + pre_kc[p] * 8;
      s8v chunk;
      if (phase == 0) {
        chunk = *(const s8v*)&h[(size_t)gR * NCH + gk];
      } else if (phase == 1) {
        chunk = *(const s8v*)&p1[(size_t)gR * NCH + gk];
      } else {
        union { s8v v; __half2 h2[4]; } a, b, r;
        a.v = *(const s8v*)&p2[(size_t)gR * NCH + gk];
        b.v = *(const s8v*)&h[(size_t)gR * NCH + gk];
        const __half2 two = __floats2half2_rn(2.f, 2.f);
#pragma unroll
        for (int j = 0; j < 4; ++j) r.h2[j] = __hsub2(__hmul2(two, a.h2[j]), b.h2[j]);
        chunk = r.v;
      }
      *(s8v*)&As[(size_t)(p * 256 + t) * 8] = chunk;
    }
    __syncthreads();
    // fragments: a[rt][kw] at chunk slot=(w*2+rt)*2+kw, lidx=lane (contiguous per wave)
    h8v a[2][2];
#pragma unroll
    for (int rt = 0; rt < 2; ++rt)
#pragma unroll
      for (int kw = 0; kw < 2; ++kw)
        a[rt][kw] = *(const h8v*)&As[(size_t)((((w * 2 + rt) * 2 + kw) * 64) + lane) * 8];
#pragma unroll
    for (int ct = 0; ct < 8; ++ct) {
#pragma unroll
      for (int kw = 0; kw < 2; ++kw) {
        int kwin = (s & 1) * 2 + kw;
        int boff = (phase * 4 + kwin) * 4096 + ct * 512 + lane * 8;
        h8v bh = *(const h8v*)&WFhi[boff];
        h8v bl = *(const h8v*)&WFlo[boff];
#pragma unroll
        for (int rt = 0; rt < 2; ++rt) {
          accH[rt][ct] = __builtin_amdgcn_mfma_f32_16x16x32_f16(a[rt][kw], bh, accH[rt][ct], 0, 0, 0);
          accL[rt][ct] = __builtin_amdgcn_mfma_f32_16x16x32_f16(a[rt][kw], bl, accL[rt][ct], 0, 0, 0);
        }
      }
    }
  }
  // epilogue: C/D layout col = lane&15, row = (lane>>4)*4 + reg
  int crow = (lane >> 4) * 4;
  int ccol = lane & 15;
  const float inv2048 = 1.0f / 2048.0f;
#pragma unroll
  for (int rt = 0; rt < 2; ++rt) {
    int gRow0 = rowBase + (w * 2 + rt) * 16 + crow;
#pragma unroll
    for (int reg = 0; reg < 4; ++reg) {
      int gRow = gRow0 + reg;
      if (gRow >= N) continue;
#pragma unroll
      for (int ct = 0; ct < 8; ++ct) {
        int col = ct * 16 + ccol;
        float vv = accH[rt][ct][reg] + accL[rt][ct][reg] * inv2048 + bias[col];
        if (relu) vv = fmaxf(vv, 0.f);
        out[(size_t)gRow * NCH + col] = __float2half(vv);
      }
    }
  }
}

// ---------------- pooling + final linear ----------------

__global__ __launch_bounds__(128) void pool_kernel(const __half* __restrict__ h,
                                                   const int* __restrict__ batch,
                                                   float* __restrict__ sums,
                                                   float* __restrict__ gcnt, int N) {
  int start = blockIdx.x * POOL_CHUNK;
  if (start >= N) return;
  int end = min(start + POOL_CHUNK, N);
  int c = threadIdx.x;
  float acc = 0.f;
  int cnt = 0;
  int cur = batch[start];
  for (int i = start; i < end; ++i) {
    int g = batch[i];
    if (g != cur) {
      atomicAdd(&sums[cur * NCH + c], acc);
      if (c == 0) atomicAdd(&gcnt[cur], (float)cnt);
      acc = 0.f; cnt = 0; cur = g;
    }
    acc += __half2float(h[(size_t)i * NCH + c]);
    ++cnt;
  }
  atomicAdd(&sums[cur * NCH + c], acc);
  if (c == 0) atomicAdd(&gcnt[cur], (float)cnt);
}

__global__ void final_kernel(const float* __restrict__ sums, const float* __restrict__ gcnt,
                             const float* __restrict__ lw, const float* __restrict__ lb,
                             float* __restrict__ out) {
  int g = blockIdx.x;
  int o = threadIdx.x;
  if (o >= OUTC) return;
  float inv = 1.0f / fmaxf(gcnt[g], 1.0f);
  float acc = lb[o];
  for (int ch = 0; ch < NCH; ++ch) acc += sums[g * NCH + ch] * inv * lw[ch * OUTC + o];
  out[g * OUTC + o] = acc;
}

// ---------------- launch ----------------

extern "C" void kernel_launch(void* const* d_in, const int* in_sizes, int n_in,
                              void* d_out, int out_size, void* d_ws, size_t ws_size,
                              hipStream_t stream) {
  const float* x  = (const float*)d_in[0];
  const int* ei   = (const int*)d_in[1];
  const int* batch= (const int*)d_in[2];
  const float* W0 = (const float*)d_in[3];
  const float* b0 = (const float*)d_in[4];
  const float* W1 = (const float*)d_in[5];
  const float* b1 = (const float*)d_in[6];
  const float* W2 = (const float*)d_in[7];
  const float* b2 = (const float*)d_in[8];
  const float* lw = (const float*)d_in[9];
  const float* lb = (const float*)d_in[10];
  float* out = (float*)d_out;
  int N = in_sizes[0] / NCH;
  int E = in_sizes[1] / 2;

  char* ws = (char*)d_ws;
  size_t off = 0;
  auto take = [&](size_t bytes) -> char* {
    char* p = ws + off;
    off += (bytes + 511) & ~(size_t)511;
    return p;
  };
  int* sc      = (int*)take((size_t)N * 4);
  int* dc      = (int*)take((size_t)N * 4);
  float* dis   = (float*)take((size_t)N * 4);
  int* rp      = (int*)take((size_t)(N + 1) * 4);
  int* bsum    = (int*)take(1024 * 4);
  int* rank    = (int*)take((size_t)E * 4);
  int2* sedge  = (int2*)take((size_t)E * 8);
  __half* x16  = (__half*)take((size_t)N * NCH * 2);
  __half* H16  = (__half*)take((size_t)N * NCH * 2);
  __half* P1h  = (__half*)take((size_t)N * NCH * 2);
  __half* P2h  = (__half*)take((size_t)N * NCH * 2);
  __half* WFhi = (__half*)take((size_t)3 * 3 * 128 * 128 * 2);
  __half* WFlo = (__half*)take((size_t)3 * 3 * 128 * 128 * 2);
  float* sums  = (float*)take((size_t)NGRAPHS * NCH * 4);
  float* gcnt  = (float*)take((size_t)NGRAPHS * 4);

  int nb = (N + 1023) / 1024;

  hipMemsetAsync(sc, 0, (size_t)N * 4, stream);
  hipMemsetAsync(dc, 0, (size_t)N * 4, stream);
  hipMemsetAsync(sums, 0, (size_t)NGRAPHS * NCH * 4, stream);
  hipMemsetAsync(gcnt, 0, (size_t)NGRAPHS * 4, stream);

  prep_w_kernel<<<(3 * 3 * 128 * 128 + 255) / 256, 256, 0, stream>>>(W0, W1, W2, WFhi, WFlo);
  f2h_kernel<<<(N * NCH / 4 + 255) / 256, 256, 0, stream>>>(x, x16, N * NCH);
  rank_hist_kernel<<<(E + 255) / 256, 256, 0, stream>>>(ei, sc, dc, rank, E);
  dis_kernel<<<(N + 255) / 256, 256, 0, stream>>>(sc, dis, N);
  scanA_kernel<<<nb, 256, 0, stream>>>(dc, bsum, N);
  scanB_kernel<<<1, 128, 0, stream>>>(bsum, nb);
  scanC_kernel<<<nb, 256, 0, stream>>>(dc, bsum, rp, N, E);
  scatter_kernel<<<(E + 255) / 256, 256, 0, stream>>>(ei, dis, rp, rank, sedge, E);

  int pgrid = (N + 3) / 4;
  int ggrid = (N + 127) / 128;
  const int WL = 3 * 4 * 8 * 512;  // halfs per layer in WF layout

  // layer 0
  prop_kernel<<<pgrid, 256, 0, stream>>>(x16, P1h, rp, sedge, N);
  prop_kernel<<<pgrid, 256, 0, stream>>>(P1h, P2h, rp, sedge, N);
  gemm_cheb_mfma<<<ggrid, 256, 0, stream>>>(x16, P1h, P2h, WFhi + 0 * WL, WFlo + 0 * WL, b0, H16, N, 1);
  // layer 1 (out aliases h; safe per kernel comment)
  prop_kernel<<<pgrid, 256, 0, stream>>>(H16, P1h, rp, sedge, N);
  prop_kernel<<<pgrid, 256, 0, stream>>>(P1h, P2h, rp, sedge, N);
  gemm_cheb_mfma<<<ggrid, 256, 0, stream>>>(H16, P1h, P2h, WFhi + 1 * WL, WFlo + 1 * WL, b1, H16, N, 1);
  // layer 2
  prop_kernel<<<pgrid, 256, 0, stream>>>(H16, P1h, rp, sedge, N);
  prop_kernel<<<pgrid, 256, 0, stream>>>(P1h, P2h, rp, sedge, N);
  gemm_cheb_mfma<<<ggrid, 256, 0, stream>>>(H16, P1h, P2h, WFhi + 2 * WL, WFlo + 2 * WL, b2, H16, N, 0);

  pool_kernel<<<(N + POOL_CHUNK - 1) / POOL_CHUNK, 128, 0, stream>>>(H16, batch, sums, gcnt, N);
  final_kernel<<<NGRAPHS, 16, 0, stream>>>(sums, gcnt, lw, lb, out);
}

// Round 7
// 927.780 us; speedup vs baseline: 1.6064x; 1.0517x over previous
//
#include <hip/hip_runtime.h>
#include <hip/hip_fp16.h>
#include <cstdint>

#define NCH 128
#define NGRAPHS 64
#define OUTC 10
#define POOL_CHUNK 256
#define NRANGE 8

typedef __attribute__((ext_vector_type(8))) short s8v;
typedef __attribute__((ext_vector_type(8))) _Float16 h8v;
typedef __attribute__((ext_vector_type(4))) float f4v;

// ---------------- preprocessing ----------------

// fused: src-degree histogram + dst count + per-edge rank within dst bucket
__global__ __launch_bounds__(256) void rank_hist_kernel(const int* __restrict__ ei,
                                                        int* __restrict__ sc,
                                                        int* __restrict__ dc,
                                                        int* __restrict__ rank, int E) {
  int i = blockIdx.x * 256 + threadIdx.x;
  if (i >= E) return;
  atomicAdd(&sc[ei[i]], 1);
  rank[i] = atomicAdd(&dc[ei[E + i]], 1);
}

__global__ __launch_bounds__(256) void dis_kernel(const int* __restrict__ sc,
                                                  float* __restrict__ dis, int N) {
  int i = blockIdx.x * 256 + threadIdx.x;
  if (i < N) {
    int d = sc[i];
    dis[i] = d > 0 ? rsqrtf((float)d) : 0.0f;
  }
}

__global__ __launch_bounds__(256) void f2h_kernel(const float* __restrict__ in,
                                                  __half* __restrict__ out, int n) {
  int i = (blockIdx.x * 256 + threadIdx.x) * 4;
  if (i + 3 < n) {
    float4 v = *(const float4*)&in[i];
    __half2 a = __float22half2_rn(make_float2(v.x, v.y));
    __half2 b = __float22half2_rn(make_float2(v.z, v.w));
    *(__half2*)&out[i] = a;
    *(__half2*)&out[i + 2] = b;
  } else {
    for (; i < n; ++i) out[i] = __float2half(in[i]);
  }
}

__global__ __launch_bounds__(256) void scanA_kernel(const int* __restrict__ cnt,
                                                    int* __restrict__ bsum, int N) {
  __shared__ int wred[4];
  int t = threadIdx.x;
  int idx = blockIdx.x * 1024 + t * 4;
  int s = 0;
#pragma unroll
  for (int j = 0; j < 4; ++j)
    if (idx + j < N) s += cnt[idx + j];
  for (int d = 32; d; d >>= 1) s += __shfl_down(s, d);
  if ((t & 63) == 0) wred[t >> 6] = s;
  __syncthreads();
  if (t == 0) bsum[blockIdx.x] = wred[0] + wred[1] + wred[2] + wred[3];
}

__global__ void scanB_kernel(int* __restrict__ bsum, int nb) {
  __shared__ int wtot[2];
  __shared__ int carry_s;
  int t = threadIdx.x;  // 128 threads
  if (t == 0) carry_s = 0;
  __syncthreads();
  for (int base = 0; base < nb; base += 128) {
    int i = base + t;
    int v = (i < nb) ? bsum[i] : 0;
    int lane = t & 63, w = t >> 6;
    int ps = v;
    for (int d = 1; d < 64; d <<= 1) {
      int o = __shfl_up(ps, d);
      if (lane >= d) ps += o;
    }
    if (lane == 63) wtot[w] = ps;
    __syncthreads();
    int excl = ps - v + (w ? wtot[0] : 0) + carry_s;
    if (i < nb) bsum[i] = excl;
    __syncthreads();
    if (t == 0) carry_s += wtot[0] + wtot[1];
    __syncthreads();
  }
}

__global__ __launch_bounds__(256) void scanC_kernel(const int* __restrict__ cnt,
                                                    const int* __restrict__ bsum,
                                                    int* __restrict__ rp, int N, int E) {
  __shared__ int wsum[4];
  int t = threadIdx.x;
  int idx = blockIdx.x * 1024 + t * 4;
  int v[4];
#pragma unroll
  for (int j = 0; j < 4; ++j) v[j] = (idx + j < N) ? cnt[idx + j] : 0;
  int s = v[0] + v[1] + v[2] + v[3];
  int lane = t & 63, w = t >> 6;
  int ps = s;
  for (int d = 1; d < 64; d <<= 1) {
    int o = __shfl_up(ps, d);
    if (lane >= d) ps += o;
  }
  if (lane == 63) wsum[w] = ps;
  __syncthreads();
  int woff = 0;
  for (int i = 0; i < w; ++i) woff += wsum[i];
  int off = bsum[blockIdx.x] + woff + ps - s;
#pragma unroll
  for (int j = 0; j < 4; ++j) {
    if (idx + j < N) {
      rp[idx + j] = off;
      off += v[j];
    }
  }
  if (blockIdx.x == 0 && t == 0) rp[N] = E;
}

// atomic-free scatter, range-partitioned by dst so each range's writes stay in a
// ~1.6 MB L2-resident window (lines fill before eviction -> ~8x less write traffic)
__global__ __launch_bounds__(256) void scatter_kernel(const int* __restrict__ ei,
                                                      const float* __restrict__ dis,
                                                      const int* __restrict__ rp,
                                                      const int* __restrict__ rank,
                                                      int2* __restrict__ sedge, int E, int N) {
  int rng = (N + NRANGE - 1) / NRANGE;
  int lo = blockIdx.y * rng;
  int hi = min(lo + rng, N);
  int stride = gridDim.x * 256;
  for (int i = blockIdx.x * 256 + threadIdx.x; i < E; i += stride) {
    int d = ei[E + i];
    if (d < lo || d >= hi) continue;
    int s = ei[i];
    sedge[rp[d] + rank[i]] = make_int2(s, __float_as_int(-dis[s] * dis[d]));
  }
}

// --- weight prep: transpose + fp16 hi/lo(x2^11) split into MFMA-fragment-linear layout ---
__global__ __launch_bounds__(256) void prep_w_kernel(const float* __restrict__ W0,
                                                     const float* __restrict__ W1,
                                                     const float* __restrict__ W2,
                                                     __half* __restrict__ WFhi,
                                                     __half* __restrict__ WFlo) {
  int idx = blockIdx.x * 256 + threadIdx.x;
  const int TOT = 3 * 3 * 128 * 128;
  if (idx >= TOT) return;
  int j = idx & 7;
  int lane = (idx >> 3) & 63;
  int ct = (idx >> 9) & 7;
  int kwin = (idx >> 12) & 3;
  int p = (idx >> 14) % 3;
  int L = idx / (3 * 16384);
  int k = kwin * 32 + (lane >> 4) * 8 + j;
  int col = ct * 16 + (lane & 15);
  const float* W = (L == 0) ? W0 : ((L == 1) ? W1 : W2);
  float v = W[(p * 128 + k) * 128 + col];
  __half hi = __float2half_rn(v);
  float resid = v - __half2float(hi);
  __half lo = __float2half_rn(resid * 2048.0f);  // scaled to stay normal in fp16
  WFhi[idx] = hi;
  WFlo[idx] = lo;
}

// ---------------- propagate (fp16 operand): out[i] = sum_e norm_e * h[src_e] ----------------
// Wave halves each own one edge: lane reads 8B (4 channels); one gather instruction
// fetches TWO 256B rows. Cross-half reduce via shfl_xor(32) at the end.

__global__ __launch_bounds__(256) void prop_kernel(const __half* __restrict__ h,
                                                   __half* __restrict__ out,
                                                   const int* __restrict__ rp,
                                                   const int2* __restrict__ sedge, int N) {
  int node = blockIdx.x * 4 + (threadIdx.x >> 6);
  if (node >= N) return;
  int lane = threadIdx.x & 63;
  int half = lane >> 5;
  int c = (lane & 31) * 4;
  int e0 = rp[node], e1 = rp[node + 1];
  float a0 = 0.f, a1 = 0.f, a2 = 0.f, a3 = 0.f;
  int e = e0;
  for (; e + 8 <= e1; e += 8) {
#pragma unroll
    for (int u = 0; u < 4; ++u) {
      int2 Ed = sedge[e + 2 * u + half];
      float w = __int_as_float(Ed.y);
      uint2 raw = *(const uint2*)&h[(size_t)Ed.x * NCH + c];
      __half2 p = *(__half2*)&raw.x, q = *(__half2*)&raw.y;
      float2 f0 = __half22float2(p), f1 = __half22float2(q);
      a0 += w * f0.x; a1 += w * f0.y; a2 += w * f1.x; a3 += w * f1.y;
    }
  }
  if (e < e1) {
#pragma unroll
    for (int u = 0; u < 4; ++u) {
      int idx = e + 2 * u + half;
      if (idx < e1) {  // uniform per half-wave -> masked half issues no loads
        int2 Ed = sedge[idx];
        float w = __int_as_float(Ed.y);
        uint2 raw = *(const uint2*)&h[(size_t)Ed.x * NCH + c];
        __half2 p = *(__half2*)&raw.x, q = *(__half2*)&raw.y;
        float2 f0 = __half22float2(p), f1 = __half22float2(q);
        a0 += w * f0.x; a1 += w * f0.y; a2 += w * f1.x; a3 += w * f1.y;
      }
    }
  }
  a0 += __shfl_xor(a0, 32); a1 += __shfl_xor(a1, 32);
  a2 += __shfl_xor(a2, 32); a3 += __shfl_xor(a3, 32);
  if (half == 0) {
    __half2 r0 = __float22half2_rn(make_float2(a0, a1));
    __half2 r1 = __float22half2_rn(make_float2(a2, a3));
    uint2 st;
    st.x = *(unsigned*)&r0;
    st.y = *(unsigned*)&r1;
    *(uint2*)&out[(size_t)node * NCH + c] = st;
  }
}

// ------- fused Cheb GEMM via native f16 MFMA: out = h@W0 + p1@W1 + (2*p2-h)@W2 + b -------
// All activations fp16 (A fragments exact in f16 MFMA). W = Whi + Wlo/2048 via dual
// fp32 accumulators. out may alias h: each block reads only its own rows (before the
// final barrier) and writes those rows in the epilogue; blocks own disjoint rows.
__global__ __launch_bounds__(256) void gemm_cheb_mfma(
    const __half* h, const __half* p1, const __half* p2,
    const __half* __restrict__ WFhi,  // this layer: [p][kwin][ct][lane][8]
    const __half* __restrict__ WFlo,
    const float* __restrict__ bias, __half* out, int N, int relu) {
  __shared__ __align__(16) __half As[1024 * 8];
  int t = threadIdx.x;
  int w = t >> 6, lane = t & 63;
  int rowBase = blockIdx.x * 128;

  f4v accH[2][8], accL[2][8];
#pragma unroll
  for (int rt = 0; rt < 2; ++rt)
#pragma unroll
    for (int ct = 0; ct < 8; ++ct) { accH[rt][ct] = (f4v)0.f; accL[rt][ct] = (f4v)0.f; }

  int pre_row[4], pre_kc[4];
#pragma unroll
  for (int p = 0; p < 4; ++p) {
    int g = p * 256 + t;
    int slot = g >> 6, lidx = g & 63;
    pre_row[p] = (slot >> 2) * 32 + ((slot >> 1) & 1) * 16 + (lidx & 15);
    pre_kc[p] = (slot & 1) * 4 + (lidx >> 4);
  }

  for (int s = 0; s < 6; ++s) {
    int phase = s >> 1;
    int k0 = (s & 1) * 64;
    if (s) __syncthreads();
#pragma unroll
    for (int p = 0; p < 4; ++p) {
      int gRow = rowBase + pre_row[p];
      int gR = min(gRow, N - 1);
      int gk = k0 + pre_kc[p] * 8;
      s8v chunk;
      if (phase == 0) {
        chunk = *(const s8v*)&h[(size_t)gR * NCH + gk];
      } else if (phase == 1) {
        chunk = *(const s8v*)&p1[(size_t)gR * NCH + gk];
      } else {
        union { s8v v; __half2 h2[4]; } a, b, r;
        a.v = *(const s8v*)&p2[(size_t)gR * NCH + gk];
        b.v = *(const s8v*)&h[(size_t)gR * NCH + gk];
        const __half2 two = __floats2half2_rn(2.f, 2.f);
#pragma unroll
        for (int j = 0; j < 4; ++j) r.h2[j] = __hsub2(__hmul2(two, a.h2[j]), b.h2[j]);
        chunk = r.v;
      }
      *(s8v*)&As[(size_t)(p * 256 + t) * 8] = chunk;
    }
    __syncthreads();
    h8v a[2][2];
#pragma unroll
    for (int rt = 0; rt < 2; ++rt)
#pragma unroll
      for (int kw = 0; kw < 2; ++kw)
        a[rt][kw] = *(const h8v*)&As[(size_t)((((w * 2 + rt) * 2 + kw) * 64) + lane) * 8];
#pragma unroll
    for (int ct = 0; ct < 8; ++ct) {
#pragma unroll
      for (int kw = 0; kw < 2; ++kw) {
        int kwin = (s & 1) * 2 + kw;
        int boff = (phase * 4 + kwin) * 4096 + ct * 512 + lane * 8;
        h8v bh = *(const h8v*)&WFhi[boff];
        h8v bl = *(const h8v*)&WFlo[boff];
#pragma unroll
        for (int rt = 0; rt < 2; ++rt) {
          accH[rt][ct] = __builtin_amdgcn_mfma_f32_16x16x32_f16(a[rt][kw], bh, accH[rt][ct], 0, 0, 0);
          accL[rt][ct] = __builtin_amdgcn_mfma_f32_16x16x32_f16(a[rt][kw], bl, accL[rt][ct], 0, 0, 0);
        }
      }
    }
  }
  int crow = (lane >> 4) * 4;
  int ccol = lane & 15;
  const float inv2048 = 1.0f / 2048.0f;
#pragma unroll
  for (int rt = 0; rt < 2; ++rt) {
    int gRow0 = rowBase + (w * 2 + rt) * 16 + crow;
#pragma unroll
    for (int reg = 0; reg < 4; ++reg) {
      int gRow = gRow0 + reg;
      if (gRow >= N) continue;
#pragma unroll
      for (int ct = 0; ct < 8; ++ct) {
        int col = ct * 16 + ccol;
        float vv = accH[rt][ct][reg] + accL[rt][ct][reg] * inv2048 + bias[col];
        if (relu) vv = fmaxf(vv, 0.f);
        out[(size_t)gRow * NCH + col] = __float2half(vv);
      }
    }
  }
}

// ---------------- pooling + final linear ----------------

__global__ __launch_bounds__(128) void pool_kernel(const __half* __restrict__ h,
                                                   const int* __restrict__ batch,
                                                   float* __restrict__ sums,
                                                   float* __restrict__ gcnt, int N) {
  int start = blockIdx.x * POOL_CHUNK;
  if (start >= N) return;
  int end = min(start + POOL_CHUNK, N);
  int c = threadIdx.x;
  float acc = 0.f;
  int cnt = 0;
  int cur = batch[start];
  for (int i = start; i < end; ++i) {
    int g = batch[i];
    if (g != cur) {
      atomicAdd(&sums[cur * NCH + c], acc);
      if (c == 0) atomicAdd(&gcnt[cur], (float)cnt);
      acc = 0.f; cnt = 0; cur = g;
    }
    acc += __half2float(h[(size_t)i * NCH + c]);
    ++cnt;
  }
  atomicAdd(&sums[cur * NCH + c], acc);
  if (c == 0) atomicAdd(&gcnt[cur], (float)cnt);
}

__global__ void final_kernel(const float* __restrict__ sums, const float* __restrict__ gcnt,
                             const float* __restrict__ lw, const float* __restrict__ lb,
                             float* __restrict__ out) {
  int g = blockIdx.x;
  int o = threadIdx.x;
  if (o >= OUTC) return;
  float inv = 1.0f / fmaxf(gcnt[g], 1.0f);
  float acc = lb[o];
  for (int ch = 0; ch < NCH; ++ch) acc += sums[g * NCH + ch] * inv * lw[ch * OUTC + o];
  out[g * OUTC + o] = acc;
}

// ---------------- launch ----------------

extern "C" void kernel_launch(void* const* d_in, const int* in_sizes, int n_in,
                              void* d_out, int out_size, void* d_ws, size_t ws_size,
                              hipStream_t stream) {
  const float* x  = (const float*)d_in[0];
  const int* ei   = (const int*)d_in[1];
  const int* batch= (const int*)d_in[2];
  const float* W0 = (const float*)d_in[3];
  const float* b0 = (const float*)d_in[4];
  const float* W1 = (const float*)d_in[5];
  const float* b1 = (const float*)d_in[6];
  const float* W2 = (const float*)d_in[7];
  const float* b2 = (const float*)d_in[8];
  const float* lw = (const float*)d_in[9];
  const float* lb = (const float*)d_in[10];
  float* out = (float*)d_out;
  int N = in_sizes[0] / NCH;
  int E = in_sizes[1] / 2;

  char* ws = (char*)d_ws;
  size_t off = 0;
  auto take = [&](size_t bytes) -> char* {
    char* p = ws + off;
    off += (bytes + 511) & ~(size_t)511;
    return p;
  };
  int* sc      = (int*)take((size_t)N * 4);
  int* dc      = (int*)take((size_t)N * 4);
  float* dis   = (float*)take((size_t)N * 4);
  int* rp      = (int*)take((size_t)(N + 1) * 4);
  int* bsum    = (int*)take(1024 * 4);
  int* rank    = (int*)take((size_t)E * 4);
  int2* sedge  = (int2*)take((size_t)E * 8);
  __half* x16  = (__half*)take((size_t)N * NCH * 2);
  __half* H16  = (__half*)take((size_t)N * NCH * 2);
  __half* P1h  = (__half*)take((size_t)N * NCH * 2);
  __half* P2h  = (__half*)take((size_t)N * NCH * 2);
  __half* WFhi = (__half*)take((size_t)3 * 3 * 128 * 128 * 2);
  __half* WFlo = (__half*)take((size_t)3 * 3 * 128 * 128 * 2);
  float* sums  = (float*)take((size_t)NGRAPHS * NCH * 4);
  float* gcnt  = (float*)take((size_t)NGRAPHS * 4);

  int nb = (N + 1023) / 1024;

  hipMemsetAsync(sc, 0, (size_t)N * 4, stream);
  hipMemsetAsync(dc, 0, (size_t)N * 4, stream);
  hipMemsetAsync(sums, 0, (size_t)NGRAPHS * NCH * 4, stream);
  hipMemsetAsync(gcnt, 0, (size_t)NGRAPHS * 4, stream);

  prep_w_kernel<<<(3 * 3 * 128 * 128 + 255) / 256, 256, 0, stream>>>(W0, W1, W2, WFhi, WFlo);
  f2h_kernel<<<(N * NCH / 4 + 255) / 256, 256, 0, stream>>>(x, x16, N * NCH);
  rank_hist_kernel<<<(E + 255) / 256, 256, 0, stream>>>(ei, sc, dc, rank, E);
  dis_kernel<<<(N + 255) / 256, 256, 0, stream>>>(sc, dis, N);
  scanA_kernel<<<nb, 256, 0, stream>>>(dc, bsum, N);
  scanB_kernel<<<1, 128, 0, stream>>>(bsum, nb);
  scanC_kernel<<<nb, 256, 0, stream>>>(dc, bsum, rp, N, E);
  {
    dim3 sg(512, NRANGE, 1);
    scatter_kernel<<<sg, 256, 0, stream>>>(ei, dis, rp, rank, sedge, E, N);
  }

  int pgrid = (N + 3) / 4;
  int ggrid = (N + 127) / 128;
  const int WL = 3 * 4 * 8 * 512;  // halfs per layer in WF layout

  // layer 0
  prop_kernel<<<pgrid, 256, 0, stream>>>(x16, P1h, rp, sedge, N);
  prop_kernel<<<pgrid, 256, 0, stream>>>(P1h, P2h, rp, sedge, N);
  gemm_cheb_mfma<<<ggrid, 256, 0, stream>>>(x16, P1h, P2h, WFhi + 0 * WL, WFlo + 0 * WL, b0, H16, N, 1);
  // layer 1 (out aliases h; safe per kernel comment)
  prop_kernel<<<pgrid, 256, 0, stream>>>(H16, P1h, rp, sedge, N);
  prop_kernel<<<pgrid, 256, 0, stream>>>(P1h, P2h, rp, sedge, N);
  gemm_cheb_mfma<<<ggrid, 256, 0, stream>>>(H16, P1h, P2h, WFhi + 1 * WL, WFlo + 1 * WL, b1, H16, N, 1);
  // layer 2
  prop_kernel<<<pgrid, 256, 0, stream>>>(H16, P1h, rp, sedge, N);
  prop_kernel<<<pgrid, 256, 0, stream>>>(P1h, P2h, rp, sedge, N);
  gemm_cheb_mfma<<<ggrid, 256, 0, stream>>>(H16, P1h, P2h, WFhi + 2 * WL, WFlo + 2 * WL, b2, H16, N, 0);

  pool_kernel<<<(N + POOL_CHUNK - 1) / POOL_CHUNK, 128, 0, stream>>>(H16, batch, sums, gcnt, N);
  final_kernel<<<NGRAPHS, 16, 0, stream>>>(sums, gcnt, lw, lb, out);
}